// Round 8
// baseline (635.091 us; speedup 1.0000x reference)
//
#include <hip/hip_runtime.h>

// Viterbi detector, bit-exact vs f32 reference.
// Lane-relabeled trellis: lane l holds state pi_phi(l), phase phi = t&3.
// Labelings are GF(2)-linear, chosen so the ACS partner exchange is a
// single-DPP pattern at EVERY phase: masks (8, 2, 1, 15) =
// row_ror:8 / quad_perm[2,3,0,1] / quad_perm[1,0,3,2] / row_mirror.
//   pi_0: s = (l2, l2^l0, l2^l1, l3^l2)   (bits s0..s3)
//   pi_1: s = (l3^l2, l2, l2^l0, l2^l1)
//   pi_2: s = (l2^l1, l3^l2, l2, l2^l0)
//   pi_3: s = (l2^l0, l2^l1, l3^l2, l2)
// K1 serial forward now ALSO records decision bits (they're off the
// min->add critical chain; R3-R7 proved ~70% of issue slots are idle),
// writing dec[] directly -> k_replay AND checkpoints are eliminated.
// K3 k_maps: per-chunk 16-hypothesis traceback -> 16->16 survivor maps.
// K4 compose maps backward. K5 emit bits as floats.

#define DEV static __device__ __forceinline__

static constexpr int T_OUT = 16384;   // output bits per seq
static constexpr int TT    = 16388;   // T + MEM steps
static constexpr int BB    = 256;     // batch
static constexpr int CHUNK = 64;
static constexpr int NFULL = 256;     // full 64-step chunks
static constexpr int NC    = 257;     // + 4-step tail chunk

// inverse labelings, nibble-packed: lane = (IPI_TAB[phi] >> (4*s)) & 15
static constexpr unsigned long long IPI_TAB[4] = {
  0x4b5a6978c3d2e1f0ULL,   // pi_0^-1
  0x4cb35da26e917f80ULL,   // pi_1^-1
  0x46ceb93157dfa820ULL,   // pi_2^-1
  0x4567cdefba983210ULL,   // pi_3^-1
};

DEV int pi_of(int phi, int l){
  int l0=l&1, l1=(l>>1)&1, l2=(l>>2)&1, l3=(l>>3)&1;
  switch(phi & 3){
    case 0:  return (l2)      | ((l2^l0)<<1) | ((l2^l1)<<2) | ((l3^l2)<<3);
    case 1:  return (l3^l2)   | ((l2)<<1)    | ((l2^l0)<<2) | ((l2^l1)<<3);
    case 2:  return (l2^l1)   | ((l3^l2)<<1) | ((l2)<<2)    | ((l2^l0)<<3);
    default: return (l2^l0)   | ((l2^l1)<<1) | ((l3^l2)<<2) | ((l2)<<3);
  }
}

template<int CTRL>
DEV float dppmov(float x){
  return __int_as_float(__builtin_amdgcn_update_dpp(0, __float_as_int(x), CTRL, 0xF, 0xF, true));
}

// partner exchange per phase: masks 8, 2, 1, 15 (all single DPP)
template<int PH>
DEV float partner_of(float p){
  if constexpr (PH == 0) return dppmov<0x128>(p);   // row_ror:8      -> ^8
  else if constexpr (PH == 1) return dppmov<0x4E>(p);    // quad[2,3,0,1] -> ^2
  else if constexpr (PH == 2) return dppmov<0xB1>(p);    // quad[1,0,3,2] -> ^1
  else return dppmov<0x140>(p);                          // row_mirror    -> ^15
}

// expected[s] = sum_j (1-2*bit_j(s)) * h[j], sequential f32 accumulation
DEV float exp_of_state(int s, float h0, float h1, float h2, float h3){
  float e =            ((s     ) & 1) ? -h0 : h0;
  e = __fadd_rn(e, (((s >> 1)) & 1) ? -h1 : h1);
  e = __fadd_rn(e, (((s >> 2)) & 1) ? -h2 : h2);
  e = __fadd_rn(e, (((s >> 3)) & 1) ? -h3 : h3);
  return e;
}

// one ACS step + decision bit. The min path uses partner_of(p) in a
// single-use form so the DPP-combiner can fuse v_min_f32_dpp (2-op
// chain: min->add); the decision uses a SECOND dppmov + 2 cmps, all
// off the critical chain (filling idle issue slots).
// role = (in-state bit3); d = strict (cand_b1 < cand_b0), tie -> 0.
template<int PH>
DEV unsigned fstep(float& p, float yv, float E, bool role){
  float dd   = __fsub_rn(yv, E);
  float cost = __fmul_rn(dd, dd);
  float partner = partner_of<PH>(p);            // off-chain copy for decision
  unsigned d = (role ? (p < partner) : (partner < p)) ? 1u : 0u;
  p = __fadd_rn(fminf(p, partner_of<PH>(p)), cost);   // fusable min_dpp
  return d;
}

// async global->LDS, 16B per lane; no destination VGPRs, tracked by vmcnt.
DEV void gload_lds16(const float* g, float* l){
  __builtin_amdgcn_global_load_lds(
      (const __attribute__((address_space(1))) void*)(g),
      (__attribute__((address_space(3))) void*)(l), 16, 0, 0);
}

// ---------------- K1: serial forward -> decision bits ----------------
__global__ __launch_bounds__(64, 1) void k_forward(const float* __restrict__ y,
                                                   const float* __restrict__ h,
                                                   unsigned long long* __restrict__ dec){
  __shared__ float ring[8][256];   // 8 x (64 steps x 4 seqs); layout g*16+s*4+(t&3)

  const int lane = threadIdx.x & 63;
  const int l16  = lane & 15;
  const int s4   = lane >> 4;            // seq-in-block of the COMPUTE role
  const float h0 = h[0], h1 = h[1], h2 = h[2], h3 = h[3];
  const float EA = exp_of_state(pi_of(1,l16), h0,h1,h2,h3);
  const float EB = exp_of_state(pi_of(2,l16), h0,h1,h2,h3);
  const float EC = exp_of_state(pi_of(3,l16), h0,h1,h2,h3);
  const float ED = exp_of_state(pi_of(0,l16), h0,h1,h2,h3);
  const bool r0 = (((l16>>3) ^ (l16>>2)) & 1) != 0;   // bit3 of pi_0(l)
  const bool r1 = (((l16>>2) ^ (l16>>1)) & 1) != 0;   // bit3 of pi_1(l)
  const bool r2 = (((l16>>2) ^  l16    ) & 1) != 0;   // bit3 of pi_2(l)
  const bool r3 = (( l16>>2)             & 1) != 0;   // bit3 of pi_3(l)
  const int  seq4 = blockIdx.x * 4 + s4;

  // staging role: lane l sources seq (l&3), 16B at float (l>>2)*4 of the chunk.
  // LDS dest linear lane*16B == consumer layout ring[buf][g*16+s*4+j].
  const float* ysrc = y + (size_t)(blockIdx.x * 4 + (lane & 3)) * TT + (lane >> 2) * 4;

  // prologue: prefetch chunks 0..5
  #pragma unroll
  for (int k = 0; k < 6; ++k)
    gload_lds16(ysrc + k * CHUNK, &ring[k][0]);

  float p = 0.0f;                     // in0 = zeros
  for (int c = 0; c < NFULL; ++c){
    const int ckLoad = (c + 6 < NFULL) ? c + 6 : NFULL - 1;
    gload_lds16(ysrc + ckLoad * CHUNK, &ring[(c + 6) & 7][0]);
    // stores also count in vmcnt; in-order retirement: >=6 newer ops
    // always follow load(c), so vmcnt(6) guarantees chunk c is in LDS
    // (effective lead ~3 chunks ~ 1900cy > HBM 900cy).
    asm volatile("s_waitcnt vmcnt(6)" ::: "memory");
    __builtin_amdgcn_sched_barrier(0);

    const float* buf = &ring[c & 7][0];
    float4 r[16];
    #pragma unroll
    for (int g = 0; g < 16; ++g)
      r[g] = *(const float4*)(buf + g * 16 + s4 * 4);

    unsigned lo = 0, hi = 0;
    #pragma unroll
    for (int g = 0; g < 16; ++g){
      unsigned d0 = fstep<0>(p, r[g].x, EA, r0);
      unsigned d1 = fstep<1>(p, r[g].y, EB, r1);
      unsigned d2 = fstep<2>(p, r[g].z, EC, r2);
      unsigned d3 = fstep<3>(p, r[g].w, ED, r3);
      const int t = 4 * g;
      if (t < 32) lo |= (d0 << t) | (d1 << (t+1)) | (d2 << (t+2)) | (d3 << (t+3));
      else        hi |= (d0 << (t-32)) | (d1 << (t-31)) | (d2 << (t-30)) | (d3 << (t-29));
    }
    dec[((size_t)c * BB + seq4) * 16 + l16] = ((unsigned long long)hi << 32) | lo;
  }

  // tail chunk (4 steps, t = 16384..16387; phases 0..3)
  {
    const float4 yv = *(const float4*)(y + (size_t)seq4 * TT + NFULL * CHUNK);
    unsigned d0 = fstep<0>(p, yv.x, EA, r0);
    unsigned d1 = fstep<1>(p, yv.y, EB, r1);
    unsigned d2 = fstep<2>(p, yv.z, EC, r2);
    unsigned d3 = fstep<3>(p, yv.w, ED, r3);
    unsigned tl = d0 | (d1 << 1) | (d2 << 2) | (d3 << 3);
    dec[((size_t)NFULL * BB + seq4) * 16 + l16] = (unsigned long long)tl;
  }
}

// ---------------- K3: per-chunk 16-hypothesis traceback -> maps ----------------
__global__ __launch_bounds__(256) void k_maps(const unsigned long long* __restrict__ dec,
                                              unsigned char* __restrict__ map){
  const int gt   = blockIdx.x * 256 + threadIdx.x;
  const int pair = gt >> 4;
  const int e    = gt & 15;        // end-state hypothesis; also this lane's word index
  const int c    = pair >> 8;
  const unsigned long long w = dec[(size_t)pair * 16 + e];
  const unsigned wlo = (unsigned)w, whi = (unsigned)(w >> 32);
  const int base = (threadIdx.x & 63) & 48;
  int s = e;
  if (c < NFULL){
    #pragma unroll
    for (int j = 63; j >= 0; --j){
      int l = (int)((IPI_TAB[(j + 1) & 3] >> (4 * s)) & 15);
      unsigned hw = __shfl((j >= 32) ? whi : wlo, base + l);
      int b = (hw >> (j & 31)) & 1;
      s = (s >> 1) | (b << 3);
    }
  } else {
    #pragma unroll
    for (int j = 3; j >= 0; --j){
      int l = (int)((IPI_TAB[(j + 1) & 3] >> (4 * s)) & 15);
      unsigned hw = __shfl(wlo, base + l);
      int b = (hw >> j) & 1;
      s = (s >> 1) | (b << 3);
    }
  }
  map[(size_t)pair * 16 + e] = (unsigned char)s;
}

// ---------------- K4: compose maps backward -> chunk end states ----------------
__global__ __launch_bounds__(256) void k_compose(const unsigned char* __restrict__ map,
                                                 unsigned char* __restrict__ Earr){
  const int seq = threadIdx.x;
  int s = 0;
  Earr[(size_t)NFULL * BB + seq] = 0;              // end state of tail chunk = 0
  #pragma unroll 4
  for (int c = NC - 1; c >= 1; --c){
    const uint4 mr = *(const uint4*)(map + ((size_t)c * BB + seq) * 16);
    unsigned wsel = (s < 8) ? ((s < 4) ? mr.x : mr.y) : ((s < 12) ? mr.z : mr.w);
    s = (wsel >> ((s & 3) * 8)) & 15;
    Earr[(size_t)(c - 1) * BB + seq] = (unsigned char)s;
  }
}

// ---------------- K5: re-trace from known end state, emit floats ----------------
__global__ __launch_bounds__(256) void k_emit(const unsigned long long* __restrict__ dec,
                                              const unsigned char* __restrict__ Earr,
                                              float* __restrict__ out){
  const int gt   = blockIdx.x * 256 + threadIdx.x;
  const int pair = gt >> 4;        // c*256+seq, c < 256
  const int l16  = gt & 15;
  const int c    = pair >> 8;
  const int seq  = pair & 255;
  const unsigned long long w = dec[(size_t)pair * 16 + l16];
  const unsigned wlo = (unsigned)w, whi = (unsigned)(w >> 32);
  const int base = (threadIdx.x & 63) & 48;
  int s = Earr[(size_t)c * BB + seq];
  float4 f = make_float4(0.f, 0.f, 0.f, 0.f);
  #pragma unroll
  for (int j = 63; j >= 0; --j){
    int l = (int)((IPI_TAB[(j + 1) & 3] >> (4 * s)) & 15);
    unsigned hw = __shfl((j >= 32) ? whi : wlo, base + l);
    int b = (hw >> (j & 31)) & 1;
    s = (s >> 1) | (b << 3);
    float fb = (float)b;           // output bit at n = 64*c + j
    if (l16 == (j >> 2)){
      if      ((j & 3) == 0) f.x = fb;
      else if ((j & 3) == 1) f.y = fb;
      else if ((j & 3) == 2) f.z = fb;
      else                   f.w = fb;
    }
  }
  *(float4*)(out + (size_t)seq * T_OUT + c * CHUNK + l16 * 4) = f;
}

extern "C" void kernel_launch(void* const* d_in, const int* in_sizes, int n_in,
                              void* d_out, int out_size, void* d_ws, size_t ws_size,
                              hipStream_t stream){
  const float* y = (const float*)d_in[0];
  const float* h = (const float*)d_in[1];
  float* out = (float*)d_out;

  const size_t DEC_B  = (size_t)NC * BB * 16 * 8;           // 8,421,376
  const size_t MAP_B  = (size_t)NC * BB * 16;               // 1,052,672
  const size_t E_B    = (size_t)NC * BB;                    //    65,792
  if (ws_size < DEC_B + MAP_B + E_B) return;

  char* ws = (char*)d_ws;
  unsigned long long* dec  = (unsigned long long*)ws;
  unsigned char*      map  = (unsigned char*)(ws + DEC_B);
  unsigned char*      Earr = (unsigned char*)(ws + DEC_B + MAP_B);

  hipLaunchKernelGGL(k_forward, dim3(64),   dim3(64),  0, stream, y, h, dec);
  hipLaunchKernelGGL(k_maps,    dim3(4112), dim3(256), 0, stream, dec, map);
  hipLaunchKernelGGL(k_compose, dim3(1),    dim3(256), 0, stream, map, Earr);
  hipLaunchKernelGGL(k_emit,    dim3(4096), dim3(256), 0, stream, dec, Earr, out);
}

// Round 9
// 428.150 us; speedup vs baseline: 1.4833x; 1.4833x over previous
//
#include <hip/hip_runtime.h>

// Viterbi detector, bit-exact vs f32 reference.
// Lane-relabeled trellis: lane l holds state pi_phi(l), phase phi = t&3.
// GF(2)-linear labelings -> ACS partner exchange is a single-DPP pattern
// at EVERY phase: masks (8, 2, 1, 15).
//   pi_0: s = (l2, l2^l0, l2^l1, l3^l2)   (bits s0..s3)
//   pi_1: s = (l3^l2, l2, l2^l0, l2^l1)
//   pi_2: s = (l2^l1, l3^l2, l2, l2^l0)
//   pi_3: s = (l2^l0, l2^l1, l3^l2, l2)
// R9 EXPERIMENT: DVFS heater. k_forward runs 64 real blocks + 448 heater
// blocks (dependent-FMA spin, device-scope flag exit) to raise the DPM
// shader clock during the latency-bound serial phase. R3-R8 evidence:
// per-step cost pinned at ~43 "2.4GHz-cy" across 4 schedules vs ~12-14 cy
// modeled -> suspected ~3x downclock under 64-wave load.
// K2 replay -> decision bits + fused in-register traceback maps.
// K4 compose. K5 emit bits as floats.

#define DEV static __device__ __forceinline__

static constexpr int T_OUT = 16384;   // output bits per seq
static constexpr int TT    = 16388;   // T + MEM steps
static constexpr int BB    = 256;     // batch
static constexpr int CHUNK = 64;
static constexpr int NFULL = 256;     // full 64-step chunks
static constexpr int NC    = 257;     // + 4-step tail chunk
static constexpr int REAL_BLOCKS = 64;
static constexpr int GRID_FWD    = 512;   // 64 real + 448 heater

// inverse labelings, nibble-packed: lane = (IPI_TAB[phi] >> (4*s)) & 15
static constexpr unsigned long long IPI_TAB[4] = {
  0x4b5a6978c3d2e1f0ULL,   // pi_0^-1
  0x4cb35da26e917f80ULL,   // pi_1^-1
  0x46ceb93157dfa820ULL,   // pi_2^-1
  0x4567cdefba983210ULL,   // pi_3^-1
};

DEV int pi_of(int phi, int l){
  int l0=l&1, l1=(l>>1)&1, l2=(l>>2)&1, l3=(l>>3)&1;
  switch(phi & 3){
    case 0:  return (l2)      | ((l2^l0)<<1) | ((l2^l1)<<2) | ((l3^l2)<<3);
    case 1:  return (l3^l2)   | ((l2)<<1)    | ((l2^l0)<<2) | ((l2^l1)<<3);
    case 2:  return (l2^l1)   | ((l3^l2)<<1) | ((l2)<<2)    | ((l2^l0)<<3);
    default: return (l2^l0)   | ((l2^l1)<<1) | ((l3^l2)<<2) | ((l2)<<3);
  }
}

template<int CTRL>
DEV float dppmov(float x){
  return __int_as_float(__builtin_amdgcn_update_dpp(0, __float_as_int(x), CTRL, 0xF, 0xF, true));
}

// partner exchange per phase: masks 8, 2, 1, 15 (all single DPP)
template<int PH>
DEV float partner_of(float p){
  if constexpr (PH == 0) return dppmov<0x128>(p);   // row_ror:8      -> ^8
  else if constexpr (PH == 1) return dppmov<0x4E>(p);    // quad[2,3,0,1] -> ^2
  else if constexpr (PH == 2) return dppmov<0xB1>(p);    // quad[1,0,3,2] -> ^1
  else return dppmov<0x140>(p);                          // row_mirror    -> ^15
}

// expected[s] = sum_j (1-2*bit_j(s)) * h[j], sequential f32 accumulation
DEV float exp_of_state(int s, float h0, float h1, float h2, float h3){
  float e =            ((s     ) & 1) ? -h0 : h0;
  e = __fadd_rn(e, (((s >> 1)) & 1) ? -h1 : h1);
  e = __fadd_rn(e, (((s >> 2)) & 1) ? -h2 : h2);
  e = __fadd_rn(e, (((s >> 3)) & 1) ? -h3 : h3);
  return e;
}

// one ACS step: p = min(p, dpp(p)) + (y-E)^2
template<int PH>
DEV void vstep(float& p, float yv, float E){
  float d    = __fsub_rn(yv, E);
  float cost = __fmul_rn(d, d);
  p = __fadd_rn(fminf(p, partner_of<PH>(p)), cost);
}

// async global->LDS, 16B per lane; no destination VGPRs, tracked by vmcnt.
DEV void gload_lds16(const float* g, float* l){
  __builtin_amdgcn_global_load_lds(
      (const __attribute__((address_space(1))) void*)(g),
      (__attribute__((address_space(3))) void*)(l), 16, 0, 0);
}

// ---------------- K0: reset done-flag (graph-capture-safe) ----------------
__global__ void k_zero(unsigned* __restrict__ flag){ *flag = 0u; }

// ---------------- K1: serial forward + heater ----------------
__global__ __launch_bounds__(64, 1) void k_forward(const float* __restrict__ y,
                                                   const float* __restrict__ h,
                                                   float* __restrict__ ckpt,
                                                   unsigned* __restrict__ flag){
  if (blockIdx.x >= REAL_BLOCKS){
    // ---- heater: dependent-FMA spin to hold the DPM shader clock up ----
    float a = 1.0f + (float)(threadIdx.x);
    const float bm = 1.0000001f, cm = 1.0e-7f;
    for (int it = 0; it < 100000; ++it){
      #pragma unroll
      for (int k = 0; k < 16; ++k) a = __builtin_fmaf(a, bm, cm);
      if ((it & 3) == 3){
        if (__hip_atomic_load(flag, __ATOMIC_RELAXED, __HIP_MEMORY_SCOPE_AGENT)
            >= (unsigned)REAL_BLOCKS) break;
      }
    }
    asm volatile("" :: "v"(a));   // keep the chain live
    return;
  }

  __shared__ float ring[8][256];   // 8 x (64 steps x 4 seqs); layout g*16+s*4+(t&3)
  __shared__ float cks[64 * 64];   // 64-chunk segment of checkpoints [ch][s][16]

  const int lane = threadIdx.x & 63;
  const int l16  = lane & 15;
  const int s4   = lane >> 4;            // seq-in-block of the COMPUTE role
  const float h0 = h[0], h1 = h[1], h2 = h[2], h3 = h[3];
  const float EA = exp_of_state(pi_of(1,l16), h0,h1,h2,h3);
  const float EB = exp_of_state(pi_of(2,l16), h0,h1,h2,h3);
  const float EC = exp_of_state(pi_of(3,l16), h0,h1,h2,h3);
  const float ED = exp_of_state(pi_of(0,l16), h0,h1,h2,h3);
  const int   st0 = pi_of(0, l16);

  // staging role: lane l sources seq (l&3), 16B at float (l>>2)*4 of the chunk.
  // LDS dest linear lane*16B == consumer layout ring[buf][g*16+s*4+j].
  const float* ysrc = y + (size_t)(blockIdx.x * 4 + (lane & 3)) * TT + (lane >> 2) * 4;

  // prologue: prefetch chunks 0..5
  #pragma unroll
  for (int k = 0; k < 6; ++k)
    gload_lds16(ysrc + k * CHUNK, &ring[k][0]);

  float p = 0.0f;                     // in0 = zeros
  for (int c = 0; c < NFULL; ++c){
    const int ckLoad = (c + 6 < NFULL) ? c + 6 : NFULL - 1;
    gload_lds16(ysrc + ckLoad * CHUNK, &ring[(c + 6) & 7][0]);
    asm volatile("s_waitcnt vmcnt(6)" ::: "memory");
    __builtin_amdgcn_sched_barrier(0);

    const float* buf = &ring[c & 7][0];
    float4 r[16];
    #pragma unroll
    for (int g = 0; g < 16; ++g)
      r[g] = *(const float4*)(buf + g * 16 + s4 * 4);
    #pragma unroll
    for (int g = 0; g < 16; ++g){
      vstep<0>(p, r[g].x, EA);
      vstep<1>(p, r[g].y, EB);
      vstep<2>(p, r[g].z, EC);
      vstep<3>(p, r[g].w, ED);
    }
    cks[(c & 63) * 64 + s4 * 16 + st0] = p;

    if ((c & 63) == 63){
      const int seg = c >> 6;
      #pragma unroll 8
      for (int ch = 0; ch < 64; ++ch){
        const size_t chunkIdx = (size_t)seg * 64 + ch;
        ckpt[(chunkIdx * BB + blockIdx.x * 4) * 16 + lane] = cks[ch * 64 + lane];
      }
      asm volatile("s_waitcnt vmcnt(0)" ::: "memory");
      __builtin_amdgcn_sched_barrier(0);
    }
  }

  if (threadIdx.x == 0)
    atomicAdd(flag, 1u);    // signal heaters: this block is done
}

// ---------------- K2: replay -> decision bits + fused traceback map --------
// role = (in-state bit3) per phase; decision d = strict (cand_b1 < cand_b0).
template<int PH>
DEV unsigned rstep(float& p, float yv, float E, bool role){
  float partner = partner_of<PH>(p);
  float c1 = role ? p : partner;
  float c0 = role ? partner : p;
  unsigned d = (c1 < c0) ? 1u : 0u;
  float mn = fminf(p, partner);
  float dd = __fsub_rn(yv, E);
  p = __fadd_rn(mn, __fmul_rn(dd, dd));
  return d;
}

__global__ __launch_bounds__(256) void k_replay(const float* __restrict__ y,
                                                const float* __restrict__ h,
                                                const float* __restrict__ ckpt,
                                                unsigned long long* __restrict__ dec,
                                                unsigned char* __restrict__ map){
  const int gt   = blockIdx.x * 256 + threadIdx.x;
  const int pair = gt >> 4;              // c*256 + seq
  const int l16  = gt & 15;
  const int c    = pair >> 8;
  const int seq  = pair & 255;
  const float h0 = h[0], h1 = h[1], h2 = h[2], h3 = h[3];
  const float EA = exp_of_state(pi_of(1,l16), h0,h1,h2,h3);
  const float EB = exp_of_state(pi_of(2,l16), h0,h1,h2,h3);
  const float EC = exp_of_state(pi_of(3,l16), h0,h1,h2,h3);
  const float ED = exp_of_state(pi_of(0,l16), h0,h1,h2,h3);
  const bool r0 = (((l16>>3) ^ (l16>>2)) & 1) != 0;   // bit3 of pi_0(l)
  const bool r1 = (((l16>>2) ^ (l16>>1)) & 1) != 0;   // bit3 of pi_1(l)
  const bool r2 = (((l16>>2) ^  l16    ) & 1) != 0;   // bit3 of pi_2(l)
  const bool r3 = (( l16>>2)             & 1) != 0;   // bit3 of pi_3(l)
  const int  st0 = pi_of(0, l16);

  float p = (c == 0) ? 0.0f : ckpt[((size_t)(c - 1) * BB + seq) * 16 + st0];
  const float* yc = y + (size_t)seq * TT + c * CHUNK;
  unsigned lo = 0, hi = 0;

  if (c < NFULL){
    #pragma unroll
    for (int g = 0; g < 16; ++g){
      float4 yv = *(const float4*)(yc + 4*g);
      unsigned d0 = rstep<0>(p, yv.x, EA, r0);
      unsigned d1 = rstep<1>(p, yv.y, EB, r1);
      unsigned d2 = rstep<2>(p, yv.z, EC, r2);
      unsigned d3 = rstep<3>(p, yv.w, ED, r3);
      const int t = 4 * g;
      if (t < 32) lo |= (d0 << t) | (d1 << (t+1)) | (d2 << (t+2)) | (d3 << (t+3));
      else        hi |= (d0 << (t-32)) | (d1 << (t-31)) | (d2 << (t-30)) | (d3 << (t-29));
    }
  } else {
    float4 yv = *(const float4*)(yc);
    unsigned d0 = rstep<0>(p, yv.x, EA, r0);
    unsigned d1 = rstep<1>(p, yv.y, EB, r1);
    unsigned d2 = rstep<2>(p, yv.z, EC, r2);
    unsigned d3 = rstep<3>(p, yv.w, ED, r3);
    lo = d0 | (d1 << 1) | (d2 << 2) | (d3 << 3);
  }
  dec[(size_t)pair * 16 + l16] = ((unsigned long long)hi << 32) | lo;

  // ---- fused traceback: words are in this 16-lane group's registers ----
  const int base = (threadIdx.x & 63) & 48;
  int s = l16;                         // end-state hypothesis e = l16
  if (c < NFULL){
    #pragma unroll
    for (int j = 63; j >= 0; --j){
      int l = (int)((IPI_TAB[(j + 1) & 3] >> (4 * s)) & 15);
      unsigned hw = __shfl((j >= 32) ? hi : lo, base + l);
      int b = (hw >> (j & 31)) & 1;
      s = (s >> 1) | (b << 3);
    }
  } else {
    #pragma unroll
    for (int j = 3; j >= 0; --j){
      int l = (int)((IPI_TAB[(j + 1) & 3] >> (4 * s)) & 15);
      unsigned hw = __shfl(lo, base + l);
      int b = (hw >> j) & 1;
      s = (s >> 1) | (b << 3);
    }
  }
  map[(size_t)pair * 16 + l16] = (unsigned char)s;
}

// ---------------- K4: compose maps backward -> chunk end states ----------------
__global__ __launch_bounds__(256) void k_compose(const unsigned char* __restrict__ map,
                                                 unsigned char* __restrict__ Earr){
  const int seq = threadIdx.x;
  int s = 0;
  Earr[(size_t)NFULL * BB + seq] = 0;              // end state of tail chunk = 0
  #pragma unroll 4
  for (int c = NC - 1; c >= 1; --c){
    const uint4 mr = *(const uint4*)(map + ((size_t)c * BB + seq) * 16);
    unsigned wsel = (s < 8) ? ((s < 4) ? mr.x : mr.y) : ((s < 12) ? mr.z : mr.w);
    s = (wsel >> ((s & 3) * 8)) & 15;
    Earr[(size_t)(c - 1) * BB + seq] = (unsigned char)s;
  }
}

// ---------------- K5: re-trace from known end state, emit floats ----------------
__global__ __launch_bounds__(256) void k_emit(const unsigned long long* __restrict__ dec,
                                              const unsigned char* __restrict__ Earr,
                                              float* __restrict__ out){
  const int gt   = blockIdx.x * 256 + threadIdx.x;
  const int pair = gt >> 4;        // c*256+seq, c < 256
  const int l16  = gt & 15;
  const int c    = pair >> 8;
  const int seq  = pair & 255;
  const unsigned long long w = dec[(size_t)pair * 16 + l16];
  const unsigned wlo = (unsigned)w, whi = (unsigned)(w >> 32);
  const int base = (threadIdx.x & 63) & 48;
  int s = Earr[(size_t)c * BB + seq];
  float4 f = make_float4(0.f, 0.f, 0.f, 0.f);
  #pragma unroll
  for (int j = 63; j >= 0; --j){
    int l = (int)((IPI_TAB[(j + 1) & 3] >> (4 * s)) & 15);
    unsigned hw = __shfl((j >= 32) ? whi : wlo, base + l);
    int b = (hw >> (j & 31)) & 1;
    s = (s >> 1) | (b << 3);
    float fb = (float)b;           // output bit at n = 64*c + j
    if (l16 == (j >> 2)){
      if      ((j & 3) == 0) f.x = fb;
      else if ((j & 3) == 1) f.y = fb;
      else if ((j & 3) == 2) f.z = fb;
      else                   f.w = fb;
    }
  }
  *(float4*)(out + (size_t)seq * T_OUT + c * CHUNK + l16 * 4) = f;
}

extern "C" void kernel_launch(void* const* d_in, const int* in_sizes, int n_in,
                              void* d_out, int out_size, void* d_ws, size_t ws_size,
                              hipStream_t stream){
  const float* y = (const float*)d_in[0];
  const float* h = (const float*)d_in[1];
  float* out = (float*)d_out;

  const size_t CKPT_B = (size_t)NFULL * BB * 16 * 4;        // 4,194,304
  const size_t DEC_B  = (size_t)NC * BB * 16 * 8;           // 8,421,376
  const size_t MAP_B  = (size_t)NC * BB * 16;               // 1,052,672
  const size_t E_B    = (size_t)NC * BB;                    //    65,792
  const size_t FLAG_B = 128;
  if (ws_size < CKPT_B + DEC_B + MAP_B + E_B + FLAG_B) return;

  char* ws = (char*)d_ws;
  float*              ckpt = (float*)ws;
  unsigned long long* dec  = (unsigned long long*)(ws + CKPT_B);
  unsigned char*      map  = (unsigned char*)(ws + CKPT_B + DEC_B);
  unsigned char*      Earr = (unsigned char*)(ws + CKPT_B + DEC_B + MAP_B);
  unsigned*           flag = (unsigned*)(ws + CKPT_B + DEC_B + MAP_B + E_B);

  hipLaunchKernelGGL(k_zero,    dim3(1),        dim3(1),   0, stream, flag);
  hipLaunchKernelGGL(k_forward, dim3(GRID_FWD), dim3(64),  0, stream, y, h, ckpt, flag);
  hipLaunchKernelGGL(k_replay,  dim3(4112),     dim3(256), 0, stream, y, h, ckpt, dec, map);
  hipLaunchKernelGGL(k_compose, dim3(1),        dim3(256), 0, stream, map, Earr);
  hipLaunchKernelGGL(k_emit,    dim3(4096),     dim3(256), 0, stream, dec, Earr, out);
}

// Round 10
// 406.295 us; speedup vs baseline: 1.5631x; 1.0538x over previous
//
#include <hip/hip_runtime.h>

// Viterbi detector, bit-exact vs f32 reference.
// Lane-relabeled trellis: lane l holds state pi_phi(l), phase phi = t&3.
// GF(2)-linear labelings -> ACS partner exchange is a single-DPP pattern
// at EVERY phase: masks (8, 2, 1, 15).
//   pi_0: s = (l2, l2^l0, l2^l1, l3^l2)   (bits s0..s3)
//   pi_1: s = (l3^l2, l2, l2^l0, l2^l1)
//   pi_2: s = (l2^l1, l3^l2, l2, l2^l0)
//   pi_3: s = (l2^l0, l2^l1, l3^l2, l2)
// K1 serial forward (fused min_dpp chain, global_load_lds ring, counted
// vmcnt) -> checkpoints. K2 replay: decisions + fused 16-hypothesis
// traceback, emitting BOTH the 16->16 survivor map AND the 64 path bits
// per hypothesis (bits[] replaces dec[] -> k_emit needs no re-trace).
// K4 compose maps -> chunk end states. K5 emit = pure-BW bit expansion.

#define DEV static __device__ __forceinline__

static constexpr int T_OUT = 16384;   // output bits per seq
static constexpr int TT    = 16388;   // T + MEM steps
static constexpr int BB    = 256;     // batch
static constexpr int CHUNK = 64;
static constexpr int NFULL = 256;     // full 64-step chunks
static constexpr int NC    = 257;     // + 4-step tail chunk

// inverse labelings, nibble-packed: lane = (IPI_TAB[phi] >> (4*s)) & 15
static constexpr unsigned long long IPI_TAB[4] = {
  0x4b5a6978c3d2e1f0ULL,   // pi_0^-1
  0x4cb35da26e917f80ULL,   // pi_1^-1
  0x46ceb93157dfa820ULL,   // pi_2^-1
  0x4567cdefba983210ULL,   // pi_3^-1
};

DEV int pi_of(int phi, int l){
  int l0=l&1, l1=(l>>1)&1, l2=(l>>2)&1, l3=(l>>3)&1;
  switch(phi & 3){
    case 0:  return (l2)      | ((l2^l0)<<1) | ((l2^l1)<<2) | ((l3^l2)<<3);
    case 1:  return (l3^l2)   | ((l2)<<1)    | ((l2^l0)<<2) | ((l2^l1)<<3);
    case 2:  return (l2^l1)   | ((l3^l2)<<1) | ((l2)<<2)    | ((l2^l0)<<3);
    default: return (l2^l0)   | ((l2^l1)<<1) | ((l3^l2)<<2) | ((l2)<<3);
  }
}

template<int CTRL>
DEV float dppmov(float x){
  return __int_as_float(__builtin_amdgcn_update_dpp(0, __float_as_int(x), CTRL, 0xF, 0xF, true));
}

// partner exchange per phase: masks 8, 2, 1, 15 (all single DPP)
template<int PH>
DEV float partner_of(float p){
  if constexpr (PH == 0) return dppmov<0x128>(p);   // row_ror:8      -> ^8
  else if constexpr (PH == 1) return dppmov<0x4E>(p);    // quad[2,3,0,1] -> ^2
  else if constexpr (PH == 2) return dppmov<0xB1>(p);    // quad[1,0,3,2] -> ^1
  else return dppmov<0x140>(p);                          // row_mirror    -> ^15
}

// expected[s] = sum_j (1-2*bit_j(s)) * h[j], sequential f32 accumulation
DEV float exp_of_state(int s, float h0, float h1, float h2, float h3){
  float e =            ((s     ) & 1) ? -h0 : h0;
  e = __fadd_rn(e, (((s >> 1)) & 1) ? -h1 : h1);
  e = __fadd_rn(e, (((s >> 2)) & 1) ? -h2 : h2);
  e = __fadd_rn(e, (((s >> 3)) & 1) ? -h3 : h3);
  return e;
}

// one ACS step: p = min(p, dpp(p)) + (y-E)^2
template<int PH>
DEV void vstep(float& p, float yv, float E){
  float d    = __fsub_rn(yv, E);
  float cost = __fmul_rn(d, d);
  p = __fadd_rn(fminf(p, partner_of<PH>(p)), cost);
}

// async global->LDS, 16B per lane; no destination VGPRs, tracked by vmcnt.
DEV void gload_lds16(const float* g, float* l){
  __builtin_amdgcn_global_load_lds(
      (const __attribute__((address_space(1))) void*)(g),
      (__attribute__((address_space(3))) void*)(l), 16, 0, 0);
}

// ---------------- K1: serial forward, checkpoints only ----------------
__global__ __launch_bounds__(64, 1) void k_forward(const float* __restrict__ y,
                                                   const float* __restrict__ h,
                                                   float* __restrict__ ckpt){
  __shared__ float ring[8][256];   // 8 x (64 steps x 4 seqs); layout g*16+s*4+(t&3)
  __shared__ float cks[64 * 64];   // 64-chunk segment of checkpoints [ch][s][16]

  const int lane = threadIdx.x & 63;
  const int l16  = lane & 15;
  const int s4   = lane >> 4;            // seq-in-block of the COMPUTE role
  const float h0 = h[0], h1 = h[1], h2 = h[2], h3 = h[3];
  const float EA = exp_of_state(pi_of(1,l16), h0,h1,h2,h3);
  const float EB = exp_of_state(pi_of(2,l16), h0,h1,h2,h3);
  const float EC = exp_of_state(pi_of(3,l16), h0,h1,h2,h3);
  const float ED = exp_of_state(pi_of(0,l16), h0,h1,h2,h3);
  const int   st0 = pi_of(0, l16);

  // staging role: lane l sources seq (l&3), 16B at float (l>>2)*4 of the chunk.
  // LDS dest linear lane*16B == consumer layout ring[buf][g*16+s*4+j].
  const float* ysrc = y + (size_t)(blockIdx.x * 4 + (lane & 3)) * TT + (lane >> 2) * 4;

  // prologue: prefetch chunks 0..5
  #pragma unroll
  for (int k = 0; k < 6; ++k)
    gload_lds16(ysrc + k * CHUNK, &ring[k][0]);

  float p = 0.0f;                     // in0 = zeros
  for (int c = 0; c < NFULL; ++c){
    const int ckLoad = (c + 6 < NFULL) ? c + 6 : NFULL - 1;
    gload_lds16(ysrc + ckLoad * CHUNK, &ring[(c + 6) & 7][0]);
    asm volatile("s_waitcnt vmcnt(6)" ::: "memory");
    __builtin_amdgcn_sched_barrier(0);

    const float* buf = &ring[c & 7][0];
    float4 r[16];
    #pragma unroll
    for (int g = 0; g < 16; ++g)
      r[g] = *(const float4*)(buf + g * 16 + s4 * 4);
    #pragma unroll
    for (int g = 0; g < 16; ++g){
      vstep<0>(p, r[g].x, EA);
      vstep<1>(p, r[g].y, EB);
      vstep<2>(p, r[g].z, EC);
      vstep<3>(p, r[g].w, ED);
    }
    cks[(c & 63) * 64 + s4 * 16 + st0] = p;

    if ((c & 63) == 63){
      const int seg = c >> 6;
      #pragma unroll 8
      for (int ch = 0; ch < 64; ++ch){
        const size_t chunkIdx = (size_t)seg * 64 + ch;
        ckpt[(chunkIdx * BB + blockIdx.x * 4) * 16 + lane] = cks[ch * 64 + lane];
      }
      asm volatile("s_waitcnt vmcnt(0)" ::: "memory");
      __builtin_amdgcn_sched_barrier(0);
    }
  }
}

// ---------------- K2: replay -> traceback maps + per-hypothesis path bits ----
// role = (in-state bit3) per phase; decision d = strict (cand_b1 < cand_b0).
template<int PH>
DEV unsigned rstep(float& p, float yv, float E, bool role){
  float partner = partner_of<PH>(p);
  float c1 = role ? p : partner;
  float c0 = role ? partner : p;
  unsigned d = (c1 < c0) ? 1u : 0u;
  float mn = fminf(p, partner);
  float dd = __fsub_rn(yv, E);
  p = __fadd_rn(mn, __fmul_rn(dd, dd));
  return d;
}

__global__ __launch_bounds__(256) void k_replay(const float* __restrict__ y,
                                                const float* __restrict__ h,
                                                const float* __restrict__ ckpt,
                                                unsigned long long* __restrict__ bits,
                                                unsigned char* __restrict__ map){
  const int gt   = blockIdx.x * 256 + threadIdx.x;
  const int pair = gt >> 4;              // c*256 + seq
  const int l16  = gt & 15;
  const int c    = pair >> 8;
  const int seq  = pair & 255;
  const float h0 = h[0], h1 = h[1], h2 = h[2], h3 = h[3];
  const float EA = exp_of_state(pi_of(1,l16), h0,h1,h2,h3);
  const float EB = exp_of_state(pi_of(2,l16), h0,h1,h2,h3);
  const float EC = exp_of_state(pi_of(3,l16), h0,h1,h2,h3);
  const float ED = exp_of_state(pi_of(0,l16), h0,h1,h2,h3);
  const bool r0 = (((l16>>3) ^ (l16>>2)) & 1) != 0;   // bit3 of pi_0(l)
  const bool r1 = (((l16>>2) ^ (l16>>1)) & 1) != 0;   // bit3 of pi_1(l)
  const bool r2 = (((l16>>2) ^  l16    ) & 1) != 0;   // bit3 of pi_2(l)
  const bool r3 = (( l16>>2)             & 1) != 0;   // bit3 of pi_3(l)
  const int  st0 = pi_of(0, l16);

  float p = (c == 0) ? 0.0f : ckpt[((size_t)(c - 1) * BB + seq) * 16 + st0];
  const float* yc = y + (size_t)seq * TT + c * CHUNK;
  unsigned lo = 0, hi = 0;

  if (c < NFULL){
    #pragma unroll
    for (int g = 0; g < 16; ++g){
      float4 yv = *(const float4*)(yc + 4*g);
      unsigned d0 = rstep<0>(p, yv.x, EA, r0);
      unsigned d1 = rstep<1>(p, yv.y, EB, r1);
      unsigned d2 = rstep<2>(p, yv.z, EC, r2);
      unsigned d3 = rstep<3>(p, yv.w, ED, r3);
      const int t = 4 * g;
      if (t < 32) lo |= (d0 << t) | (d1 << (t+1)) | (d2 << (t+2)) | (d3 << (t+3));
      else        hi |= (d0 << (t-32)) | (d1 << (t-31)) | (d2 << (t-30)) | (d3 << (t-29));
    }
  } else {
    float4 yv = *(const float4*)(yc);
    unsigned d0 = rstep<0>(p, yv.x, EA, r0);
    unsigned d1 = rstep<1>(p, yv.y, EB, r1);
    unsigned d2 = rstep<2>(p, yv.z, EC, r2);
    unsigned d3 = rstep<3>(p, yv.w, ED, r3);
    lo = d0 | (d1 << 1) | (d2 << 2) | (d3 << 3);
  }

  // ---- fused traceback: decision words live in this 16-lane group's regs.
  // Lane e = end-state hypothesis; record survivor start-state AND the 64
  // path bits (bit j of pb = output bit at step j under hypothesis e).
  const int base = (threadIdx.x & 63) & 48;
  int s = l16;
  unsigned long long pb = 0ull;
  if (c < NFULL){
    #pragma unroll
    for (int j = 63; j >= 0; --j){
      int l = (int)((IPI_TAB[(j + 1) & 3] >> (4 * s)) & 15);
      unsigned hw = __shfl((j >= 32) ? hi : lo, base + l);
      unsigned long long b = (hw >> (j & 31)) & 1;
      s = (s >> 1) | ((int)b << 3);
      pb |= b << j;
    }
  } else {
    #pragma unroll
    for (int j = 3; j >= 0; --j){
      int l = (int)((IPI_TAB[(j + 1) & 3] >> (4 * s)) & 15);
      unsigned hw = __shfl(lo, base + l);
      unsigned long long b = (hw >> j) & 1;
      s = (s >> 1) | ((int)b << 3);
      pb |= b << j;
    }
  }
  bits[(size_t)pair * 16 + l16] = pb;
  map [(size_t)pair * 16 + l16] = (unsigned char)s;
}

// ---------------- K4: compose maps backward -> chunk end states ----------------
__global__ __launch_bounds__(256) void k_compose(const unsigned char* __restrict__ map,
                                                 unsigned char* __restrict__ Earr){
  const int seq = threadIdx.x;
  int s = 0;
  Earr[(size_t)NFULL * BB + seq] = 0;              // end state of tail chunk = 0
  #pragma unroll 4
  for (int c = NC - 1; c >= 1; --c){
    const uint4 mr = *(const uint4*)(map + ((size_t)c * BB + seq) * 16);
    unsigned wsel = (s < 8) ? ((s < 4) ? mr.x : mr.y) : ((s < 12) ? mr.z : mr.w);
    s = (wsel >> ((s & 3) * 8)) & 15;
    Earr[(size_t)(c - 1) * BB + seq] = (unsigned char)s;
  }
}

// ---------------- K5: emit = select hypothesis, expand bits to floats --------
__global__ __launch_bounds__(256) void k_emit(const unsigned long long* __restrict__ bits,
                                              const unsigned char* __restrict__ Earr,
                                              float* __restrict__ out){
  const int gt   = blockIdx.x * 256 + threadIdx.x;
  const int pair = gt >> 4;        // c*256+seq, c < 256
  const int l16  = gt & 15;
  const int c    = pair >> 8;
  const int seq  = pair & 255;
  const int e    = Earr[(size_t)c * BB + seq];             // broadcast in group
  const unsigned long long w = bits[(size_t)pair * 16 + e];// broadcast in group
  const int j0 = l16 * 4;
  float4 f;
  f.x = (float)((w >> (j0    )) & 1);
  f.y = (float)((w >> (j0 + 1)) & 1);
  f.z = (float)((w >> (j0 + 2)) & 1);
  f.w = (float)((w >> (j0 + 3)) & 1);
  *(float4*)(out + (size_t)seq * T_OUT + c * CHUNK + j0) = f;
}

extern "C" void kernel_launch(void* const* d_in, const int* in_sizes, int n_in,
                              void* d_out, int out_size, void* d_ws, size_t ws_size,
                              hipStream_t stream){
  const float* y = (const float*)d_in[0];
  const float* h = (const float*)d_in[1];
  float* out = (float*)d_out;

  const size_t CKPT_B = (size_t)NFULL * BB * 16 * 4;        // 4,194,304
  const size_t BITS_B = (size_t)NC * BB * 16 * 8;           // 8,421,376
  const size_t MAP_B  = (size_t)NC * BB * 16;               // 1,052,672
  const size_t E_B    = (size_t)NC * BB;                    //    65,792
  if (ws_size < CKPT_B + BITS_B + MAP_B + E_B) return;

  char* ws = (char*)d_ws;
  float*              ckpt = (float*)ws;
  unsigned long long* bits = (unsigned long long*)(ws + CKPT_B);
  unsigned char*      map  = (unsigned char*)(ws + CKPT_B + BITS_B);
  unsigned char*      Earr = (unsigned char*)(ws + CKPT_B + BITS_B + MAP_B);

  hipLaunchKernelGGL(k_forward, dim3(64),   dim3(64),  0, stream, y, h, ckpt);
  hipLaunchKernelGGL(k_replay,  dim3(4112), dim3(256), 0, stream, y, h, ckpt, bits, map);
  hipLaunchKernelGGL(k_compose, dim3(1),    dim3(256), 0, stream, map, Earr);
  hipLaunchKernelGGL(k_emit,    dim3(4096), dim3(256), 0, stream, bits, Earr, out);
}

// Round 11
// 386.432 us; speedup vs baseline: 1.6435x; 1.0514x over previous
//
#include <hip/hip_runtime.h>

// Viterbi detector, bit-exact vs f32 reference.
// Lane-relabeled trellis: lane l holds state pi_phi(l), phase phi = t&3.
// GF(2)-linear labelings -> ACS partner exchange is a single-DPP pattern
// at EVERY phase: masks (8, 2, 1, 15).
//   pi_0: s = (l2, l2^l0, l2^l1, l3^l2)   (bits s0..s3)
//   pi_1: s = (l3^l2, l2, l2^l0, l2^l1)
//   pi_2: s = (l2^l1, l3^l2, l2, l2^l0)
//   pi_3: s = (l2^l0, l2^l1, l3^l2, l2)
// K1 serial forward: HAND-SCHEDULED asm 4-step group. R10 counters showed
// the wave issues only 44% of cycles (VALUBusy 2.77% vs 6.25% ceiling):
// in-order issue leaves min-latency + DPP-hazard slots empty because the
// compiler orders cost ops AFTER the dependent add. The asm block
// software-pipelines the (y-E)^2 ops into those slots (>=1 VALU instr =
// 2cy = the s_nop-1 hazard gap proven bit-exact in R3-R5).
// K2 replay: decisions + fused 16-hypothesis traceback -> survivor map +
// 64 path bits/hypothesis. K4 compose. K5 emit = pure-BW bit expansion.

#define DEV static __device__ __forceinline__

static constexpr int T_OUT = 16384;   // output bits per seq
static constexpr int TT    = 16388;   // T + MEM steps
static constexpr int BB    = 256;     // batch
static constexpr int CHUNK = 64;
static constexpr int NFULL = 256;     // full 64-step chunks
static constexpr int NC    = 257;     // + 4-step tail chunk

// inverse labelings, nibble-packed: lane = (IPI_TAB[phi] >> (4*s)) & 15
static constexpr unsigned long long IPI_TAB[4] = {
  0x4b5a6978c3d2e1f0ULL,   // pi_0^-1
  0x4cb35da26e917f80ULL,   // pi_1^-1
  0x46ceb93157dfa820ULL,   // pi_2^-1
  0x4567cdefba983210ULL,   // pi_3^-1
};

DEV int pi_of(int phi, int l){
  int l0=l&1, l1=(l>>1)&1, l2=(l>>2)&1, l3=(l>>3)&1;
  switch(phi & 3){
    case 0:  return (l2)      | ((l2^l0)<<1) | ((l2^l1)<<2) | ((l3^l2)<<3);
    case 1:  return (l3^l2)   | ((l2)<<1)    | ((l2^l0)<<2) | ((l2^l1)<<3);
    case 2:  return (l2^l1)   | ((l3^l2)<<1) | ((l2)<<2)    | ((l2^l0)<<3);
    default: return (l2^l0)   | ((l2^l1)<<1) | ((l3^l2)<<2) | ((l2)<<3);
  }
}

template<int CTRL>
DEV float dppmov(float x){
  return __int_as_float(__builtin_amdgcn_update_dpp(0, __float_as_int(x), CTRL, 0xF, 0xF, true));
}

// partner exchange per phase: masks 8, 2, 1, 15 (all single DPP)
template<int PH>
DEV float partner_of(float p){
  if constexpr (PH == 0) return dppmov<0x128>(p);   // row_ror:8      -> ^8
  else if constexpr (PH == 1) return dppmov<0x4E>(p);    // quad[2,3,0,1] -> ^2
  else if constexpr (PH == 2) return dppmov<0xB1>(p);    // quad[1,0,3,2] -> ^1
  else return dppmov<0x140>(p);                          // row_mirror    -> ^15
}

// expected[s] = sum_j (1-2*bit_j(s)) * h[j], sequential f32 accumulation
DEV float exp_of_state(int s, float h0, float h1, float h2, float h3){
  float e =            ((s     ) & 1) ? -h0 : h0;
  e = __fadd_rn(e, (((s >> 1)) & 1) ? -h1 : h1);
  e = __fadd_rn(e, (((s >> 2)) & 1) ? -h2 : h2);
  e = __fadd_rn(e, (((s >> 3)) & 1) ? -h3 : h3);
  return e;
}

// 4 trellis steps (phases 0..3), hand-scheduled:
//   p = min(p, dpp_ph(p)) + (y_ph - E_ph)^2     for ph = 0..3
// Cost sub/mul ops are placed to fill (a) the >=2cy VALU-write->DPP-read
// hazard on p (1 VALU instr = 2 cy, the s_nop-1 equivalent) and (b) the
// min latency before the dependent add. Ops and rounding identical to the
// intrinsic version -> bit-exact.
DEV void group4(float& p, float y0, float y1, float y2, float y3,
                float EA, float EB, float EC, float ED){
  float m, c0, c1, c2, c3;
  asm volatile(
    "v_sub_f32 %2, %6, %10\n\t"                                            // c0 = y0-EA
    "v_sub_f32 %3, %7, %11\n\t"                                            // c1 = y1-EB
    "v_sub_f32 %4, %8, %12\n\t"                                            // c2 = y2-EC
    "v_sub_f32 %5, %9, %13\n\t"                                            // c3 = y3-ED
    "v_mul_f32 %2, %2, %2\n\t"                                             // c0^2
    "v_mul_f32 %3, %3, %3\n\t"                                             // c1^2 (hazard gap)
    "v_min_f32_dpp %1, %0, %0 row_ror:8 row_mask:0xf bank_mask:0xf\n\t"    // ph0
    "v_mul_f32 %4, %4, %4\n\t"                                             // c2^2 (min lat)
    "v_add_f32 %0, %1, %2\n\t"                                             // p += c0
    "v_mul_f32 %5, %5, %5\n\t"                                             // c3^2 (hazard gap)
    "v_min_f32_dpp %1, %0, %0 quad_perm:[2,3,0,1] row_mask:0xf bank_mask:0xf\n\t" // ph1
    "v_add_f32 %0, %1, %3\n\t"                                             // p += c1
    "s_nop 1\n\t"                                                          // DPP hazard
    "v_min_f32_dpp %1, %0, %0 quad_perm:[1,0,3,2] row_mask:0xf bank_mask:0xf\n\t" // ph2
    "v_add_f32 %0, %1, %4\n\t"                                             // p += c2
    "s_nop 1\n\t"                                                          // DPP hazard
    "v_min_f32_dpp %1, %0, %0 row_mirror row_mask:0xf bank_mask:0xf\n\t"   // ph3
    "v_add_f32 %0, %1, %5"                                                 // p += c3
    : "+v"(p), "=&v"(m), "=&v"(c0), "=&v"(c1), "=&v"(c2), "=&v"(c3)
    : "v"(y0), "v"(y1), "v"(y2), "v"(y3),
      "v"(EA), "v"(EB), "v"(EC), "v"(ED));
}

// async global->LDS, 16B per lane; no destination VGPRs, tracked by vmcnt.
DEV void gload_lds16(const float* g, float* l){
  __builtin_amdgcn_global_load_lds(
      (const __attribute__((address_space(1))) void*)(g),
      (__attribute__((address_space(3))) void*)(l), 16, 0, 0);
}

// ---------------- K1: serial forward, checkpoints only ----------------
__global__ __launch_bounds__(64, 1) void k_forward(const float* __restrict__ y,
                                                   const float* __restrict__ h,
                                                   float* __restrict__ ckpt){
  __shared__ float ring[8][256];   // 8 x (64 steps x 4 seqs); layout g*16+s*4+(t&3)
  __shared__ float cks[64 * 64];   // 64-chunk segment of checkpoints [ch][s][16]

  const int lane = threadIdx.x & 63;
  const int l16  = lane & 15;
  const int s4   = lane >> 4;            // seq-in-block of the COMPUTE role
  const float h0 = h[0], h1 = h[1], h2 = h[2], h3 = h[3];
  const float EA = exp_of_state(pi_of(1,l16), h0,h1,h2,h3);
  const float EB = exp_of_state(pi_of(2,l16), h0,h1,h2,h3);
  const float EC = exp_of_state(pi_of(3,l16), h0,h1,h2,h3);
  const float ED = exp_of_state(pi_of(0,l16), h0,h1,h2,h3);
  const int   st0 = pi_of(0, l16);

  // staging role: lane l sources seq (l&3), 16B at float (l>>2)*4 of the chunk.
  // LDS dest linear lane*16B == consumer layout ring[buf][g*16+s*4+j].
  const float* ysrc = y + (size_t)(blockIdx.x * 4 + (lane & 3)) * TT + (lane >> 2) * 4;

  // prologue: prefetch chunks 0..5
  #pragma unroll
  for (int k = 0; k < 6; ++k)
    gload_lds16(ysrc + k * CHUNK, &ring[k][0]);

  float p = 0.0f;                     // in0 = zeros
  for (int c = 0; c < NFULL; ++c){
    const int ckLoad = (c + 6 < NFULL) ? c + 6 : NFULL - 1;
    gload_lds16(ysrc + ckLoad * CHUNK, &ring[(c + 6) & 7][0]);
    asm volatile("s_waitcnt vmcnt(6)" ::: "memory");
    __builtin_amdgcn_sched_barrier(0);

    const float* buf = &ring[c & 7][0];
    float4 r[16];
    #pragma unroll
    for (int g = 0; g < 16; ++g)
      r[g] = *(const float4*)(buf + g * 16 + s4 * 4);
    #pragma unroll
    for (int g = 0; g < 16; ++g)
      group4(p, r[g].x, r[g].y, r[g].z, r[g].w, EA, EB, EC, ED);
    cks[(c & 63) * 64 + s4 * 16 + st0] = p;

    if ((c & 63) == 63){
      const int seg = c >> 6;
      #pragma unroll 8
      for (int ch = 0; ch < 64; ++ch){
        const size_t chunkIdx = (size_t)seg * 64 + ch;
        ckpt[(chunkIdx * BB + blockIdx.x * 4) * 16 + lane] = cks[ch * 64 + lane];
      }
      asm volatile("s_waitcnt vmcnt(0)" ::: "memory");
      __builtin_amdgcn_sched_barrier(0);
    }
  }
}

// ---------------- K2: replay -> traceback maps + per-hypothesis path bits ----
// role = (in-state bit3) per phase; decision d = strict (cand_b1 < cand_b0).
template<int PH>
DEV unsigned rstep(float& p, float yv, float E, bool role){
  float partner = partner_of<PH>(p);
  float c1 = role ? p : partner;
  float c0 = role ? partner : p;
  unsigned d = (c1 < c0) ? 1u : 0u;
  float mn = fminf(p, partner);
  float dd = __fsub_rn(yv, E);
  p = __fadd_rn(mn, __fmul_rn(dd, dd));
  return d;
}

__global__ __launch_bounds__(256) void k_replay(const float* __restrict__ y,
                                                const float* __restrict__ h,
                                                const float* __restrict__ ckpt,
                                                unsigned long long* __restrict__ bits,
                                                unsigned char* __restrict__ map){
  const int gt   = blockIdx.x * 256 + threadIdx.x;
  const int pair = gt >> 4;              // c*256 + seq
  const int l16  = gt & 15;
  const int c    = pair >> 8;
  const int seq  = pair & 255;
  const float h0 = h[0], h1 = h[1], h2 = h[2], h3 = h[3];
  const float EA = exp_of_state(pi_of(1,l16), h0,h1,h2,h3);
  const float EB = exp_of_state(pi_of(2,l16), h0,h1,h2,h3);
  const float EC = exp_of_state(pi_of(3,l16), h0,h1,h2,h3);
  const float ED = exp_of_state(pi_of(0,l16), h0,h1,h2,h3);
  const bool r0 = (((l16>>3) ^ (l16>>2)) & 1) != 0;   // bit3 of pi_0(l)
  const bool r1 = (((l16>>2) ^ (l16>>1)) & 1) != 0;   // bit3 of pi_1(l)
  const bool r2 = (((l16>>2) ^  l16    ) & 1) != 0;   // bit3 of pi_2(l)
  const bool r3 = (( l16>>2)             & 1) != 0;   // bit3 of pi_3(l)
  const int  st0 = pi_of(0, l16);

  float p = (c == 0) ? 0.0f : ckpt[((size_t)(c - 1) * BB + seq) * 16 + st0];
  const float* yc = y + (size_t)seq * TT + c * CHUNK;
  unsigned lo = 0, hi = 0;

  if (c < NFULL){
    #pragma unroll
    for (int g = 0; g < 16; ++g){
      float4 yv = *(const float4*)(yc + 4*g);
      unsigned d0 = rstep<0>(p, yv.x, EA, r0);
      unsigned d1 = rstep<1>(p, yv.y, EB, r1);
      unsigned d2 = rstep<2>(p, yv.z, EC, r2);
      unsigned d3 = rstep<3>(p, yv.w, ED, r3);
      const int t = 4 * g;
      if (t < 32) lo |= (d0 << t) | (d1 << (t+1)) | (d2 << (t+2)) | (d3 << (t+3));
      else        hi |= (d0 << (t-32)) | (d1 << (t-31)) | (d2 << (t-30)) | (d3 << (t-29));
    }
  } else {
    float4 yv = *(const float4*)(yc);
    unsigned d0 = rstep<0>(p, yv.x, EA, r0);
    unsigned d1 = rstep<1>(p, yv.y, EB, r1);
    unsigned d2 = rstep<2>(p, yv.z, EC, r2);
    unsigned d3 = rstep<3>(p, yv.w, ED, r3);
    lo = d0 | (d1 << 1) | (d2 << 2) | (d3 << 3);
  }

  // ---- fused traceback: decision words live in this 16-lane group's regs.
  // Lane e = end-state hypothesis; record survivor start-state AND the 64
  // path bits (bit j of pb = output bit at step j under hypothesis e).
  const int base = (threadIdx.x & 63) & 48;
  int s = l16;
  unsigned long long pb = 0ull;
  if (c < NFULL){
    #pragma unroll
    for (int j = 63; j >= 0; --j){
      int l = (int)((IPI_TAB[(j + 1) & 3] >> (4 * s)) & 15);
      unsigned hw = __shfl((j >= 32) ? hi : lo, base + l);
      unsigned long long b = (hw >> (j & 31)) & 1;
      s = (s >> 1) | ((int)b << 3);
      pb |= b << j;
    }
  } else {
    #pragma unroll
    for (int j = 3; j >= 0; --j){
      int l = (int)((IPI_TAB[(j + 1) & 3] >> (4 * s)) & 15);
      unsigned hw = __shfl(lo, base + l);
      unsigned long long b = (hw >> j) & 1;
      s = (s >> 1) | ((int)b << 3);
      pb |= b << j;
    }
  }
  bits[(size_t)pair * 16 + l16] = pb;
  map [(size_t)pair * 16 + l16] = (unsigned char)s;
}

// ---------------- K4: compose maps backward -> chunk end states ----------------
__global__ __launch_bounds__(256) void k_compose(const unsigned char* __restrict__ map,
                                                 unsigned char* __restrict__ Earr){
  const int seq = threadIdx.x;
  int s = 0;
  Earr[(size_t)NFULL * BB + seq] = 0;              // end state of tail chunk = 0
  #pragma unroll 4
  for (int c = NC - 1; c >= 1; --c){
    const uint4 mr = *(const uint4*)(map + ((size_t)c * BB + seq) * 16);
    unsigned wsel = (s < 8) ? ((s < 4) ? mr.x : mr.y) : ((s < 12) ? mr.z : mr.w);
    s = (wsel >> ((s & 3) * 8)) & 15;
    Earr[(size_t)(c - 1) * BB + seq] = (unsigned char)s;
  }
}

// ---------------- K5: emit = select hypothesis, expand bits to floats --------
__global__ __launch_bounds__(256) void k_emit(const unsigned long long* __restrict__ bits,
                                              const unsigned char* __restrict__ Earr,
                                              float* __restrict__ out){
  const int gt   = blockIdx.x * 256 + threadIdx.x;
  const int pair = gt >> 4;        // c*256+seq, c < 256
  const int l16  = gt & 15;
  const int c    = pair >> 8;
  const int seq  = pair & 255;
  const int e    = Earr[(size_t)c * BB + seq];             // broadcast in group
  const unsigned long long w = bits[(size_t)pair * 16 + e];// broadcast in group
  const int j0 = l16 * 4;
  float4 f;
  f.x = (float)((w >> (j0    )) & 1);
  f.y = (float)((w >> (j0 + 1)) & 1);
  f.z = (float)((w >> (j0 + 2)) & 1);
  f.w = (float)((w >> (j0 + 3)) & 1);
  *(float4*)(out + (size_t)seq * T_OUT + c * CHUNK + j0) = f;
}

extern "C" void kernel_launch(void* const* d_in, const int* in_sizes, int n_in,
                              void* d_out, int out_size, void* d_ws, size_t ws_size,
                              hipStream_t stream){
  const float* y = (const float*)d_in[0];
  const float* h = (const float*)d_in[1];
  float* out = (float*)d_out;

  const size_t CKPT_B = (size_t)NFULL * BB * 16 * 4;        // 4,194,304
  const size_t BITS_B = (size_t)NC * BB * 16 * 8;           // 8,421,376
  const size_t MAP_B  = (size_t)NC * BB * 16;               // 1,052,672
  const size_t E_B    = (size_t)NC * BB;                    //    65,792
  if (ws_size < CKPT_B + BITS_B + MAP_B + E_B) return;

  char* ws = (char*)d_ws;
  float*              ckpt = (float*)ws;
  unsigned long long* bits = (unsigned long long*)(ws + CKPT_B);
  unsigned char*      map  = (unsigned char*)(ws + CKPT_B + BITS_B);
  unsigned char*      Earr = (unsigned char*)(ws + CKPT_B + BITS_B + MAP_B);

  hipLaunchKernelGGL(k_forward, dim3(64),   dim3(64),  0, stream, y, h, ckpt);
  hipLaunchKernelGGL(k_replay,  dim3(4112), dim3(256), 0, stream, y, h, ckpt, bits, map);
  hipLaunchKernelGGL(k_compose, dim3(1),    dim3(256), 0, stream, map, Earr);
  hipLaunchKernelGGL(k_emit,    dim3(4096), dim3(256), 0, stream, bits, Earr, out);
}

// Round 12
// 362.024 us; speedup vs baseline: 1.7543x; 1.0674x over previous
//
#include <hip/hip_runtime.h>

// Viterbi detector, bit-exact vs f32 reference.
// Lane-relabeled trellis: lane l holds state pi_phi(l), phase phi = t&3.
// GF(2)-linear labelings -> ACS partner exchange is a single-DPP pattern
// at EVERY phase: masks (8, 2, 1, 15).
//   pi_0: s = (l2, l2^l0, l2^l1, l3^l2)   (bits s0..s3)
//   pi_1: s = (l3^l2, l2, l2^l0, l2^l1)
//   pi_2: s = (l2^l1, l3^l2, l2, l2^l0)
//   pi_3: s = (l2^l0, l2^l1, l3^l2, l2)
// R12: slot-minimized 8-step asm block (33 slots/8 steps vs R11's 36).
// Cross-round model: wall ~ issued slots x ~5.5 nominal cy (solo-wave
// issue throttle at the observed ~1.2GHz effective clock); chain tricks,
// prefetch depth, heaters all null. 4 VALU/step is the bit-exact floor.
// K2 replay: decisions + fused 16-hypothesis traceback -> survivor map +
// 64 path bits/hypothesis. K4 compose. K5 emit = pure-BW bit expansion.

#define DEV static __device__ __forceinline__

static constexpr int T_OUT = 16384;   // output bits per seq
static constexpr int TT    = 16388;   // T + MEM steps
static constexpr int BB    = 256;     // batch
static constexpr int CHUNK = 64;
static constexpr int NFULL = 256;     // full 64-step chunks
static constexpr int NC    = 257;     // + 4-step tail chunk

// inverse labelings, nibble-packed: lane = (IPI_TAB[phi] >> (4*s)) & 15
static constexpr unsigned long long IPI_TAB[4] = {
  0x4b5a6978c3d2e1f0ULL,   // pi_0^-1
  0x4cb35da26e917f80ULL,   // pi_1^-1
  0x46ceb93157dfa820ULL,   // pi_2^-1
  0x4567cdefba983210ULL,   // pi_3^-1
};

DEV int pi_of(int phi, int l){
  int l0=l&1, l1=(l>>1)&1, l2=(l>>2)&1, l3=(l>>3)&1;
  switch(phi & 3){
    case 0:  return (l2)      | ((l2^l0)<<1) | ((l2^l1)<<2) | ((l3^l2)<<3);
    case 1:  return (l3^l2)   | ((l2)<<1)    | ((l2^l0)<<2) | ((l2^l1)<<3);
    case 2:  return (l2^l1)   | ((l3^l2)<<1) | ((l2)<<2)    | ((l2^l0)<<3);
    default: return (l2^l0)   | ((l2^l1)<<1) | ((l3^l2)<<2) | ((l2)<<3);
  }
}

template<int CTRL>
DEV float dppmov(float x){
  return __int_as_float(__builtin_amdgcn_update_dpp(0, __float_as_int(x), CTRL, 0xF, 0xF, true));
}

// partner exchange per phase: masks 8, 2, 1, 15 (all single DPP)
template<int PH>
DEV float partner_of(float p){
  if constexpr (PH == 0) return dppmov<0x128>(p);   // row_ror:8      -> ^8
  else if constexpr (PH == 1) return dppmov<0x4E>(p);    // quad[2,3,0,1] -> ^2
  else if constexpr (PH == 2) return dppmov<0xB1>(p);    // quad[1,0,3,2] -> ^1
  else return dppmov<0x140>(p);                          // row_mirror    -> ^15
}

// expected[s] = sum_j (1-2*bit_j(s)) * h[j], sequential f32 accumulation
DEV float exp_of_state(int s, float h0, float h1, float h2, float h3){
  float e =            ((s     ) & 1) ? -h0 : h0;
  e = __fadd_rn(e, (((s >> 1)) & 1) ? -h1 : h1);
  e = __fadd_rn(e, (((s >> 2)) & 1) ? -h2 : h2);
  e = __fadd_rn(e, (((s >> 3)) & 1) ? -h3 : h3);
  return e;
}

// 8 trellis steps (phases 0..3 twice), slot-minimized:
//   p = min(p, dpp_ph(p)) + (y_i - E_ph)^2
// Cost sub/mul ops fill every VALU-write->DPP-read hazard gap except one
// (single s_nop). 33 slots / 8 steps. Ops and rounding identical to the
// intrinsic version (v_min_f32 == fminf; explicit sub/mul/add) -> bit-exact.
DEV void group8(float& p,
                float y0, float y1, float y2, float y3,
                float y4, float y5, float y6, float y7,
                float EA, float EB, float EC, float ED){
  float mn, c0, c1, c2, c3, c4, c5, c6, c7;
  asm volatile(
    "v_sub_f32 %2, %10, %18\n\t"                                           // s0
    "v_sub_f32 %3, %11, %19\n\t"                                           // s1
    "v_mul_f32 %2, %2, %2\n\t"                                             // m0
    "v_mul_f32 %3, %3, %3\n\t"                                             // m1
    "v_min_f32_dpp %1, %0, %0 row_ror:8 row_mask:0xf bank_mask:0xf\n\t"    // n0
    "v_sub_f32 %4, %12, %20\n\t"                                           // s2
    "v_add_f32 %0, %1, %2\n\t"                                             // a0
    "v_mul_f32 %4, %4, %4\n\t"                                             // m2 (gap)
    "v_min_f32_dpp %1, %0, %0 quad_perm:[2,3,0,1] row_mask:0xf bank_mask:0xf\n\t" // n1
    "v_sub_f32 %5, %13, %21\n\t"                                           // s3
    "v_add_f32 %0, %1, %3\n\t"                                             // a1
    "v_mul_f32 %5, %5, %5\n\t"                                             // m3 (gap)
    "v_min_f32_dpp %1, %0, %0 quad_perm:[1,0,3,2] row_mask:0xf bank_mask:0xf\n\t" // n2
    "v_sub_f32 %6, %14, %18\n\t"                                           // s4
    "v_add_f32 %0, %1, %4\n\t"                                             // a2
    "v_mul_f32 %6, %6, %6\n\t"                                             // m4 (gap)
    "v_min_f32_dpp %1, %0, %0 row_mirror row_mask:0xf bank_mask:0xf\n\t"   // n3
    "v_sub_f32 %7, %15, %19\n\t"                                           // s5
    "v_add_f32 %0, %1, %5\n\t"                                             // a3
    "v_mul_f32 %7, %7, %7\n\t"                                             // m5 (gap)
    "v_min_f32_dpp %1, %0, %0 row_ror:8 row_mask:0xf bank_mask:0xf\n\t"    // n4
    "v_sub_f32 %8, %16, %20\n\t"                                           // s6
    "v_add_f32 %0, %1, %6\n\t"                                             // a4
    "v_mul_f32 %8, %8, %8\n\t"                                             // m6 (gap)
    "v_min_f32_dpp %1, %0, %0 quad_perm:[2,3,0,1] row_mask:0xf bank_mask:0xf\n\t" // n5
    "v_sub_f32 %9, %17, %21\n\t"                                           // s7
    "v_add_f32 %0, %1, %7\n\t"                                             // a5
    "v_mul_f32 %9, %9, %9\n\t"                                             // m7 (gap)
    "v_min_f32_dpp %1, %0, %0 quad_perm:[1,0,3,2] row_mask:0xf bank_mask:0xf\n\t" // n6
    "v_add_f32 %0, %1, %8\n\t"                                             // a6
    "s_nop 1\n\t"                                                          // gap (nothing left)
    "v_min_f32_dpp %1, %0, %0 row_mirror row_mask:0xf bank_mask:0xf\n\t"   // n7
    "v_add_f32 %0, %1, %9"                                                 // a7
    : "+v"(p), "=&v"(mn), "=&v"(c0), "=&v"(c1), "=&v"(c2), "=&v"(c3),
      "=&v"(c4), "=&v"(c5), "=&v"(c6), "=&v"(c7)
    : "v"(y0), "v"(y1), "v"(y2), "v"(y3), "v"(y4), "v"(y5), "v"(y6), "v"(y7),
      "v"(EA), "v"(EB), "v"(EC), "v"(ED));
}

// async global->LDS, 16B per lane; no destination VGPRs, tracked by vmcnt.
DEV void gload_lds16(const float* g, float* l){
  __builtin_amdgcn_global_load_lds(
      (const __attribute__((address_space(1))) void*)(g),
      (__attribute__((address_space(3))) void*)(l), 16, 0, 0);
}

// ---------------- K1: serial forward, checkpoints only ----------------
__global__ __launch_bounds__(64, 1) void k_forward(const float* __restrict__ y,
                                                   const float* __restrict__ h,
                                                   float* __restrict__ ckpt){
  __shared__ float ring[8][256];   // 8 x (64 steps x 4 seqs); layout g*16+s*4+(t&3)
  __shared__ float cks[64 * 64];   // 64-chunk segment of checkpoints [ch][s][16]

  const int lane = threadIdx.x & 63;
  const int l16  = lane & 15;
  const int s4   = lane >> 4;            // seq-in-block of the COMPUTE role
  const float h0 = h[0], h1 = h[1], h2 = h[2], h3 = h[3];
  const float EA = exp_of_state(pi_of(1,l16), h0,h1,h2,h3);
  const float EB = exp_of_state(pi_of(2,l16), h0,h1,h2,h3);
  const float EC = exp_of_state(pi_of(3,l16), h0,h1,h2,h3);
  const float ED = exp_of_state(pi_of(0,l16), h0,h1,h2,h3);
  const int   st0 = pi_of(0, l16);

  // staging role: lane l sources seq (l&3), 16B at float (l>>2)*4 of the chunk.
  // LDS dest linear lane*16B == consumer layout ring[buf][g*16+s*4+j].
  const float* ysrc = y + (size_t)(blockIdx.x * 4 + (lane & 3)) * TT + (lane >> 2) * 4;

  // prologue: prefetch chunks 0..5
  #pragma unroll
  for (int k = 0; k < 6; ++k)
    gload_lds16(ysrc + k * CHUNK, &ring[k][0]);

  float p = 0.0f;                     // in0 = zeros
  for (int c = 0; c < NFULL; ++c){
    const int ckLoad = (c + 6 < NFULL) ? c + 6 : NFULL - 1;
    gload_lds16(ysrc + ckLoad * CHUNK, &ring[(c + 6) & 7][0]);
    asm volatile("s_waitcnt vmcnt(6)" ::: "memory");
    __builtin_amdgcn_sched_barrier(0);

    const float* buf = &ring[c & 7][0];
    float4 r[16];
    #pragma unroll
    for (int g = 0; g < 16; ++g)
      r[g] = *(const float4*)(buf + g * 16 + s4 * 4);
    #pragma unroll
    for (int g = 0; g < 16; g += 2)
      group8(p, r[g].x, r[g].y, r[g].z, r[g].w,
                r[g+1].x, r[g+1].y, r[g+1].z, r[g+1].w,
             EA, EB, EC, ED);
    cks[(c & 63) * 64 + s4 * 16 + st0] = p;

    if ((c & 63) == 63){
      const int seg = c >> 6;
      #pragma unroll 8
      for (int ch = 0; ch < 64; ++ch){
        const size_t chunkIdx = (size_t)seg * 64 + ch;
        ckpt[(chunkIdx * BB + blockIdx.x * 4) * 16 + lane] = cks[ch * 64 + lane];
      }
      asm volatile("s_waitcnt vmcnt(0)" ::: "memory");
      __builtin_amdgcn_sched_barrier(0);
    }
  }
}

// ---------------- K2: replay -> traceback maps + per-hypothesis path bits ----
// role = (in-state bit3) per phase; decision d = strict (cand_b1 < cand_b0).
template<int PH>
DEV unsigned rstep(float& p, float yv, float E, bool role){
  float partner = partner_of<PH>(p);
  float c1 = role ? p : partner;
  float c0 = role ? partner : p;
  unsigned d = (c1 < c0) ? 1u : 0u;
  float mn = fminf(p, partner);
  float dd = __fsub_rn(yv, E);
  p = __fadd_rn(mn, __fmul_rn(dd, dd));
  return d;
}

__global__ __launch_bounds__(256) void k_replay(const float* __restrict__ y,
                                                const float* __restrict__ h,
                                                const float* __restrict__ ckpt,
                                                unsigned long long* __restrict__ bits,
                                                unsigned char* __restrict__ map){
  const int gt   = blockIdx.x * 256 + threadIdx.x;
  const int pair = gt >> 4;              // c*256 + seq
  const int l16  = gt & 15;
  const int c    = pair >> 8;
  const int seq  = pair & 255;
  const float h0 = h[0], h1 = h[1], h2 = h[2], h3 = h[3];
  const float EA = exp_of_state(pi_of(1,l16), h0,h1,h2,h3);
  const float EB = exp_of_state(pi_of(2,l16), h0,h1,h2,h3);
  const float EC = exp_of_state(pi_of(3,l16), h0,h1,h2,h3);
  const float ED = exp_of_state(pi_of(0,l16), h0,h1,h2,h3);
  const bool r0 = (((l16>>3) ^ (l16>>2)) & 1) != 0;   // bit3 of pi_0(l)
  const bool r1 = (((l16>>2) ^ (l16>>1)) & 1) != 0;   // bit3 of pi_1(l)
  const bool r2 = (((l16>>2) ^  l16    ) & 1) != 0;   // bit3 of pi_2(l)
  const bool r3 = (( l16>>2)             & 1) != 0;   // bit3 of pi_3(l)
  const int  st0 = pi_of(0, l16);

  float p = (c == 0) ? 0.0f : ckpt[((size_t)(c - 1) * BB + seq) * 16 + st0];
  const float* yc = y + (size_t)seq * TT + c * CHUNK;
  unsigned lo = 0, hi = 0;

  if (c < NFULL){
    #pragma unroll
    for (int g = 0; g < 16; ++g){
      float4 yv = *(const float4*)(yc + 4*g);
      unsigned d0 = rstep<0>(p, yv.x, EA, r0);
      unsigned d1 = rstep<1>(p, yv.y, EB, r1);
      unsigned d2 = rstep<2>(p, yv.z, EC, r2);
      unsigned d3 = rstep<3>(p, yv.w, ED, r3);
      const int t = 4 * g;
      if (t < 32) lo |= (d0 << t) | (d1 << (t+1)) | (d2 << (t+2)) | (d3 << (t+3));
      else        hi |= (d0 << (t-32)) | (d1 << (t-31)) | (d2 << (t-30)) | (d3 << (t-29));
    }
  } else {
    float4 yv = *(const float4*)(yc);
    unsigned d0 = rstep<0>(p, yv.x, EA, r0);
    unsigned d1 = rstep<1>(p, yv.y, EB, r1);
    unsigned d2 = rstep<2>(p, yv.z, EC, r2);
    unsigned d3 = rstep<3>(p, yv.w, ED, r3);
    lo = d0 | (d1 << 1) | (d2 << 2) | (d3 << 3);
  }

  // ---- fused traceback: decision words live in this 16-lane group's regs.
  // Lane e = end-state hypothesis; record survivor start-state AND the 64
  // path bits (bit j of pb = output bit at step j under hypothesis e).
  const int base = (threadIdx.x & 63) & 48;
  int s = l16;
  unsigned long long pb = 0ull;
  if (c < NFULL){
    #pragma unroll
    for (int j = 63; j >= 0; --j){
      int l = (int)((IPI_TAB[(j + 1) & 3] >> (4 * s)) & 15);
      unsigned hw = __shfl((j >= 32) ? hi : lo, base + l);
      unsigned long long b = (hw >> (j & 31)) & 1;
      s = (s >> 1) | ((int)b << 3);
      pb |= b << j;
    }
  } else {
    #pragma unroll
    for (int j = 3; j >= 0; --j){
      int l = (int)((IPI_TAB[(j + 1) & 3] >> (4 * s)) & 15);
      unsigned hw = __shfl(lo, base + l);
      unsigned long long b = (hw >> j) & 1;
      s = (s >> 1) | ((int)b << 3);
      pb |= b << j;
    }
  }
  bits[(size_t)pair * 16 + l16] = pb;
  map [(size_t)pair * 16 + l16] = (unsigned char)s;
}

// ---------------- K4: compose maps backward -> chunk end states ----------------
__global__ __launch_bounds__(256) void k_compose(const unsigned char* __restrict__ map,
                                                 unsigned char* __restrict__ Earr){
  const int seq = threadIdx.x;
  int s = 0;
  Earr[(size_t)NFULL * BB + seq] = 0;              // end state of tail chunk = 0
  #pragma unroll 4
  for (int c = NC - 1; c >= 1; --c){
    const uint4 mr = *(const uint4*)(map + ((size_t)c * BB + seq) * 16);
    unsigned wsel = (s < 8) ? ((s < 4) ? mr.x : mr.y) : ((s < 12) ? mr.z : mr.w);
    s = (wsel >> ((s & 3) * 8)) & 15;
    Earr[(size_t)(c - 1) * BB + seq] = (unsigned char)s;
  }
}

// ---------------- K5: emit = select hypothesis, expand bits to floats --------
__global__ __launch_bounds__(256) void k_emit(const unsigned long long* __restrict__ bits,
                                              const unsigned char* __restrict__ Earr,
                                              float* __restrict__ out){
  const int gt   = blockIdx.x * 256 + threadIdx.x;
  const int pair = gt >> 4;        // c*256+seq, c < 256
  const int l16  = gt & 15;
  const int c    = pair >> 8;
  const int seq  = pair & 255;
  const int e    = Earr[(size_t)c * BB + seq];             // broadcast in group
  const unsigned long long w = bits[(size_t)pair * 16 + e];// broadcast in group
  const int j0 = l16 * 4;
  float4 f;
  f.x = (float)((w >> (j0    )) & 1);
  f.y = (float)((w >> (j0 + 1)) & 1);
  f.z = (float)((w >> (j0 + 2)) & 1);
  f.w = (float)((w >> (j0 + 3)) & 1);
  *(float4*)(out + (size_t)seq * T_OUT + c * CHUNK + j0) = f;
}

extern "C" void kernel_launch(void* const* d_in, const int* in_sizes, int n_in,
                              void* d_out, int out_size, void* d_ws, size_t ws_size,
                              hipStream_t stream){
  const float* y = (const float*)d_in[0];
  const float* h = (const float*)d_in[1];
  float* out = (float*)d_out;

  const size_t CKPT_B = (size_t)NFULL * BB * 16 * 4;        // 4,194,304
  const size_t BITS_B = (size_t)NC * BB * 16 * 8;           // 8,421,376
  const size_t MAP_B  = (size_t)NC * BB * 16;               // 1,052,672
  const size_t E_B    = (size_t)NC * BB;                    //    65,792
  if (ws_size < CKPT_B + BITS_B + MAP_B + E_B) return;

  char* ws = (char*)d_ws;
  float*              ckpt = (float*)ws;
  unsigned long long* bits = (unsigned long long*)(ws + CKPT_B);
  unsigned char*      map  = (unsigned char*)(ws + CKPT_B + BITS_B);
  unsigned char*      Earr = (unsigned char*)(ws + CKPT_B + BITS_B + MAP_B);

  hipLaunchKernelGGL(k_forward, dim3(64),   dim3(64),  0, stream, y, h, ckpt);
  hipLaunchKernelGGL(k_replay,  dim3(4112), dim3(256), 0, stream, y, h, ckpt, bits, map);
  hipLaunchKernelGGL(k_compose, dim3(1),    dim3(256), 0, stream, map, Earr);
  hipLaunchKernelGGL(k_emit,    dim3(4096), dim3(256), 0, stream, bits, Earr, out);
}

// Round 13
// 288.566 us; speedup vs baseline: 2.2008x; 1.2546x over previous
//
#include <hip/hip_runtime.h>

// Viterbi detector, bit-exact vs f32 reference.
// Lane-relabeled trellis: lane l holds state pi_phi(l), phase phi = t&3.
// GF(2)-linear labelings -> ACS partner exchange is a single-DPP pattern
// at EVERY phase: masks (8, 2, 1, 15).
// R13: producer/consumer wave split. Slot model (validated R11->R12:
// wall ~ issued slots x ~5.5 cy) says the serial wave must issue fewer
// slots. Wave 0 = pure chain (min_dpp, add, s_nop1 = 3 slots/step, the
// bit-exact floor given the 2-wait-state DPP hazard). Waves 1-2 compute
// the (y-E)^2 costs (same __fsub_rn/__fmul_rn ops -> bit-exact) into a
// double-buffered LDS array 2 chunks ahead, fed by the global_load_lds
// ring. RAW s_barrier + lgkmcnt(0) (NOT __syncthreads: it drains
// vmcnt(0) and would serialize the ring prefetch).
// K2 replay: decisions + fused 16-hypothesis traceback -> survivor map +
// 64 path bits/hypothesis. K4 compose. K5 emit = pure-BW bit expansion.

#define DEV static __device__ __forceinline__

static constexpr int T_OUT = 16384;   // output bits per seq
static constexpr int TT    = 16388;   // T + MEM steps
static constexpr int BB    = 256;     // batch
static constexpr int CHUNK = 64;
static constexpr int NFULL = 256;     // full 64-step chunks
static constexpr int NC    = 257;     // + 4-step tail chunk
static constexpr int CROW  = 68;      // cost row stride in floats (16B-aligned, bank-spread)

// inverse labelings, nibble-packed: lane = (IPI_TAB[phi] >> (4*s)) & 15
static constexpr unsigned long long IPI_TAB[4] = {
  0x4b5a6978c3d2e1f0ULL,   // pi_0^-1
  0x4cb35da26e917f80ULL,   // pi_1^-1
  0x46ceb93157dfa820ULL,   // pi_2^-1
  0x4567cdefba983210ULL,   // pi_3^-1
};

DEV int pi_of(int phi, int l){
  int l0=l&1, l1=(l>>1)&1, l2=(l>>2)&1, l3=(l>>3)&1;
  switch(phi & 3){
    case 0:  return (l2)      | ((l2^l0)<<1) | ((l2^l1)<<2) | ((l3^l2)<<3);
    case 1:  return (l3^l2)   | ((l2)<<1)    | ((l2^l0)<<2) | ((l2^l1)<<3);
    case 2:  return (l2^l1)   | ((l3^l2)<<1) | ((l2)<<2)    | ((l2^l0)<<3);
    default: return (l2^l0)   | ((l2^l1)<<1) | ((l3^l2)<<2) | ((l2)<<3);
  }
}

template<int CTRL>
DEV float dppmov(float x){
  return __int_as_float(__builtin_amdgcn_update_dpp(0, __float_as_int(x), CTRL, 0xF, 0xF, true));
}

// partner exchange per phase: masks 8, 2, 1, 15 (all single DPP)
template<int PH>
DEV float partner_of(float p){
  if constexpr (PH == 0) return dppmov<0x128>(p);   // row_ror:8      -> ^8
  else if constexpr (PH == 1) return dppmov<0x4E>(p);    // quad[2,3,0,1] -> ^2
  else if constexpr (PH == 2) return dppmov<0xB1>(p);    // quad[1,0,3,2] -> ^1
  else return dppmov<0x140>(p);                          // row_mirror    -> ^15
}

// expected[s] = sum_j (1-2*bit_j(s)) * h[j], sequential f32 accumulation
DEV float exp_of_state(int s, float h0, float h1, float h2, float h3){
  float e =            ((s     ) & 1) ? -h0 : h0;
  e = __fadd_rn(e, (((s >> 1)) & 1) ? -h1 : h1);
  e = __fadd_rn(e, (((s >> 2)) & 1) ? -h2 : h2);
  e = __fadd_rn(e, (((s >> 3)) & 1) ? -h3 : h3);
  return e;
}

// 8 chain steps, costs PRE-SQUARED: p = min(p, dpp_ph(p)) + m_i.
// s_nop 1 = 2 wait states for the VALU-write->DPP-read hazard (R12's
// single-VALU filler = same 2 cycles, proven bit-exact).
DEV void chain8(float& p, float m0, float m1, float m2, float m3,
                float m4, float m5, float m6, float m7){
  float mn;
  asm volatile(
    "v_min_f32_dpp %1, %0, %0 row_ror:8 row_mask:0xf bank_mask:0xf\n\t"
    "v_add_f32 %0, %1, %2\n\t"
    "s_nop 1\n\t"
    "v_min_f32_dpp %1, %0, %0 quad_perm:[2,3,0,1] row_mask:0xf bank_mask:0xf\n\t"
    "v_add_f32 %0, %1, %3\n\t"
    "s_nop 1\n\t"
    "v_min_f32_dpp %1, %0, %0 quad_perm:[1,0,3,2] row_mask:0xf bank_mask:0xf\n\t"
    "v_add_f32 %0, %1, %4\n\t"
    "s_nop 1\n\t"
    "v_min_f32_dpp %1, %0, %0 row_mirror row_mask:0xf bank_mask:0xf\n\t"
    "v_add_f32 %0, %1, %5\n\t"
    "s_nop 1\n\t"
    "v_min_f32_dpp %1, %0, %0 row_ror:8 row_mask:0xf bank_mask:0xf\n\t"
    "v_add_f32 %0, %1, %6\n\t"
    "s_nop 1\n\t"
    "v_min_f32_dpp %1, %0, %0 quad_perm:[2,3,0,1] row_mask:0xf bank_mask:0xf\n\t"
    "v_add_f32 %0, %1, %7\n\t"
    "s_nop 1\n\t"
    "v_min_f32_dpp %1, %0, %0 quad_perm:[1,0,3,2] row_mask:0xf bank_mask:0xf\n\t"
    "v_add_f32 %0, %1, %8\n\t"
    "s_nop 1\n\t"
    "v_min_f32_dpp %1, %0, %0 row_mirror row_mask:0xf bank_mask:0xf\n\t"
    "v_add_f32 %0, %1, %9"
    : "+v"(p), "=&v"(mn)
    : "v"(m0), "v"(m1), "v"(m2), "v"(m3),
      "v"(m4), "v"(m5), "v"(m6), "v"(m7));
}

// async global->LDS, 16B per lane; no destination VGPRs, tracked by vmcnt.
DEV void gload_lds16(const float* g, float* l){
  __builtin_amdgcn_global_load_lds(
      (const __attribute__((address_space(1))) void*)(g),
      (__attribute__((address_space(3))) void*)(l), 16, 0, 0);
}

// raw barrier: LDS visibility only (lgkmcnt), vmcnt stays in flight.
DEV void wg_barrier(){
  asm volatile("s_waitcnt lgkmcnt(0)" ::: "memory");
  __builtin_amdgcn_s_barrier();
}

// ---------------- K1: serial forward (3 waves: 1 chain + 2 cost) -----------
__global__ __launch_bounds__(192, 1) void k_forward(const float* __restrict__ y,
                                                    const float* __restrict__ h,
                                                    float* __restrict__ ckpt){
  __shared__ float ring[8][256];          //  8 KB: y staging (64 steps x 4 seqs each)
  __shared__ float cost[2][64 * CROW];    // 34 KB: pre-squared costs, dbuf
  __shared__ float cks[64 * 64];          // 16 KB: checkpoint segment

  const int tid  = threadIdx.x;
  const int wv   = tid >> 6;
  const int lane = tid & 63;

  if (wv == 0){
    // ================= consumer: the serial chain =================
    const int l16 = lane & 15, s4 = lane >> 4;
    const int st0 = pi_of(0, l16);
    const int row = l16 * 4 + s4;

    float4 cqA[16], cqB[16];
    float p = 0.0f;                       // in0 = zeros

    wg_barrier();                         // B0: ring 0,1 ready
    wg_barrier();                         // B1: buf0 ready
    {
      const float* cb = &cost[0][0];
      #pragma unroll
      for (int g = 0; g < 16; ++g)
        cqA[g] = *(const float4*)(cb + row * CROW + 4 * g);
    }
    wg_barrier();                         // B2: buf1 ready (cqA loads drained)

    for (int k = 0; k < NFULL; k += 2){
      { // period k (even): consume cqA (chunk k), prefetch cqB <- buf1 (chunk k+1)
        const float* cb = &cost[1][0];
        #pragma unroll
        for (int g = 0; g < 16; ++g)
          cqB[g] = *(const float4*)(cb + row * CROW + 4 * g);
        __builtin_amdgcn_sched_barrier(0);
        #pragma unroll
        for (int g = 0; g < 16; g += 2)
          chain8(p, cqA[g].x, cqA[g].y, cqA[g].z, cqA[g].w,
                    cqA[g+1].x, cqA[g+1].y, cqA[g+1].z, cqA[g+1].w);
        cks[(k & 63) * 64 + s4 * 16 + st0] = p;
      }
      wg_barrier();
      { // period k+1 (odd): consume cqB (chunk k+1), prefetch cqA <- buf0 (chunk k+2)
        const float* cb = &cost[0][0];
        #pragma unroll
        for (int g = 0; g < 16; ++g)
          cqA[g] = *(const float4*)(cb + row * CROW + 4 * g);
        __builtin_amdgcn_sched_barrier(0);
        #pragma unroll
        for (int g = 0; g < 16; g += 2)
          chain8(p, cqB[g].x, cqB[g].y, cqB[g].z, cqB[g].w,
                    cqB[g+1].x, cqB[g+1].y, cqB[g+1].z, cqB[g+1].w);
        cks[((k + 1) & 63) * 64 + s4 * 16 + st0] = p;
        if (((k + 1) & 63) == 63){
          const int seg = (k + 1) >> 6;
          #pragma unroll 8
          for (int ch = 0; ch < 64; ++ch){
            const size_t chunkIdx = (size_t)seg * 64 + ch;
            ckpt[(chunkIdx * BB + blockIdx.x * 4) * 16 + lane] = cks[ch * 64 + lane];
          }
          asm volatile("s_waitcnt vmcnt(0)" ::: "memory");  // w0's own stores only
        }
      }
      wg_barrier();
    }
  } else {
    // ================= producers: costs 2 chunks ahead =================
    const int gbase = (wv - 1) * 8;       // wave1: granules 0..7, wave2: 8..15
    const int pl16  = lane >> 2;          // state-group of this cost row
    const int ps4   = lane & 3;           // seq of this cost row
    const float h0 = h[0], h1 = h[1], h2 = h[2], h3 = h[3];
    const float EA = exp_of_state(pi_of(1,pl16), h0,h1,h2,h3);
    const float EB = exp_of_state(pi_of(2,pl16), h0,h1,h2,h3);
    const float EC = exp_of_state(pi_of(3,pl16), h0,h1,h2,h3);
    const float ED = exp_of_state(pi_of(0,pl16), h0,h1,h2,h3);
    // staging role (wave 1): lane sources seq (lane&3), 16B at float (lane>>2)*4
    const float* ysrc = y + (size_t)(blockIdx.x * 4 + ps4) * TT + pl16 * 4;

    // cost producer for granule range [gbase, gbase+8) of one chunk
    #define PRODUCE(RB, CB)                                                   \
      {                                                                       \
        const float* rb = (RB);                                               \
        float* cb = (CB);                                                     \
        _Pragma("unroll")                                                     \
        for (int g2 = 0; g2 < 8; ++g2){                                       \
          const int g = gbase + g2;                                           \
          float4 yv = *(const float4*)(rb + g * 16 + ps4 * 4);                \
          float4 c; float d;                                                  \
          d = __fsub_rn(yv.x, EA); c.x = __fmul_rn(d, d);                     \
          d = __fsub_rn(yv.y, EB); c.y = __fmul_rn(d, d);                     \
          d = __fsub_rn(yv.z, EC); c.z = __fmul_rn(d, d);                     \
          d = __fsub_rn(yv.w, ED); c.w = __fmul_rn(d, d);                     \
          *(float4*)(cb + lane * CROW + 4 * g) = c;                           \
        }                                                                     \
      }

    if (wv == 1){
      #pragma unroll
      for (int q = 0; q < 8; ++q)
        gload_lds16(ysrc + q * CHUNK, &ring[q][0]);
      asm volatile("s_waitcnt vmcnt(6)" ::: "memory");  // chunks 0,1 landed
    }
    wg_barrier();                         // B0
    PRODUCE(&ring[0][0], &cost[0][0]);    // costs chunk 0
    wg_barrier();                         // B1
    PRODUCE(&ring[1][0], &cost[1][0]);    // costs chunk 1
    if (wv == 1){
      gload_lds16(ysrc + 8 * CHUNK, &ring[0][0]);
      asm volatile("s_waitcnt vmcnt(6)" ::: "memory");  // chunk 2 landed
    }
    wg_barrier();                         // B2

    for (int k = 0; k < NFULL; k += 2){
      if (k + 2 < NFULL) PRODUCE(&ring[(k + 2) & 7][0], &cost[0][0]);
      if (wv == 1){
        const int ci = (k + 9 < NFULL) ? k + 9 : NFULL - 1;
        gload_lds16(ysrc + ci * CHUNK, &ring[(k + 9) & 7][0]);
        asm volatile("s_waitcnt vmcnt(6)" ::: "memory");
      }
      wg_barrier();
      if (k + 3 < NFULL) PRODUCE(&ring[(k + 3) & 7][0], &cost[1][0]);
      if (wv == 1){
        const int ci = (k + 10 < NFULL) ? k + 10 : NFULL - 1;
        gload_lds16(ysrc + ci * CHUNK, &ring[(k + 10) & 7][0]);
        asm volatile("s_waitcnt vmcnt(6)" ::: "memory");
      }
      wg_barrier();
    }
    #undef PRODUCE
  }
}

// ---------------- K2: replay -> traceback maps + per-hypothesis path bits ----
// role = (in-state bit3) per phase; decision d = strict (cand_b1 < cand_b0).
template<int PH>
DEV unsigned rstep(float& p, float yv, float E, bool role){
  float partner = partner_of<PH>(p);
  float c1 = role ? p : partner;
  float c0 = role ? partner : p;
  unsigned d = (c1 < c0) ? 1u : 0u;
  float mn = fminf(p, partner);
  float dd = __fsub_rn(yv, E);
  p = __fadd_rn(mn, __fmul_rn(dd, dd));
  return d;
}

__global__ __launch_bounds__(256) void k_replay(const float* __restrict__ y,
                                                const float* __restrict__ h,
                                                const float* __restrict__ ckpt,
                                                unsigned long long* __restrict__ bits,
                                                unsigned char* __restrict__ map){
  const int gt   = blockIdx.x * 256 + threadIdx.x;
  const int pair = gt >> 4;              // c*256 + seq
  const int l16  = gt & 15;
  const int c    = pair >> 8;
  const int seq  = pair & 255;
  const float h0 = h[0], h1 = h[1], h2 = h[2], h3 = h[3];
  const float EA = exp_of_state(pi_of(1,l16), h0,h1,h2,h3);
  const float EB = exp_of_state(pi_of(2,l16), h0,h1,h2,h3);
  const float EC = exp_of_state(pi_of(3,l16), h0,h1,h2,h3);
  const float ED = exp_of_state(pi_of(0,l16), h0,h1,h2,h3);
  const bool r0 = (((l16>>3) ^ (l16>>2)) & 1) != 0;   // bit3 of pi_0(l)
  const bool r1 = (((l16>>2) ^ (l16>>1)) & 1) != 0;   // bit3 of pi_1(l)
  const bool r2 = (((l16>>2) ^  l16    ) & 1) != 0;   // bit3 of pi_2(l)
  const bool r3 = (( l16>>2)             & 1) != 0;   // bit3 of pi_3(l)
  const int  st0 = pi_of(0, l16);

  float p = (c == 0) ? 0.0f : ckpt[((size_t)(c - 1) * BB + seq) * 16 + st0];
  const float* yc = y + (size_t)seq * TT + c * CHUNK;
  unsigned lo = 0, hi = 0;

  if (c < NFULL){
    #pragma unroll
    for (int g = 0; g < 16; ++g){
      float4 yv = *(const float4*)(yc + 4*g);
      unsigned d0 = rstep<0>(p, yv.x, EA, r0);
      unsigned d1 = rstep<1>(p, yv.y, EB, r1);
      unsigned d2 = rstep<2>(p, yv.z, EC, r2);
      unsigned d3 = rstep<3>(p, yv.w, ED, r3);
      const int t = 4 * g;
      if (t < 32) lo |= (d0 << t) | (d1 << (t+1)) | (d2 << (t+2)) | (d3 << (t+3));
      else        hi |= (d0 << (t-32)) | (d1 << (t-31)) | (d2 << (t-30)) | (d3 << (t-29));
    }
  } else {
    float4 yv = *(const float4*)(yc);
    unsigned d0 = rstep<0>(p, yv.x, EA, r0);
    unsigned d1 = rstep<1>(p, yv.y, EB, r1);
    unsigned d2 = rstep<2>(p, yv.z, EC, r2);
    unsigned d3 = rstep<3>(p, yv.w, ED, r3);
    lo = d0 | (d1 << 1) | (d2 << 2) | (d3 << 3);
  }

  // ---- fused traceback: decision words live in this 16-lane group's regs.
  const int base = (threadIdx.x & 63) & 48;
  int s = l16;
  unsigned long long pb = 0ull;
  if (c < NFULL){
    #pragma unroll
    for (int j = 63; j >= 0; --j){
      int l = (int)((IPI_TAB[(j + 1) & 3] >> (4 * s)) & 15);
      unsigned hw = __shfl((j >= 32) ? hi : lo, base + l);
      unsigned long long b = (hw >> (j & 31)) & 1;
      s = (s >> 1) | ((int)b << 3);
      pb |= b << j;
    }
  } else {
    #pragma unroll
    for (int j = 3; j >= 0; --j){
      int l = (int)((IPI_TAB[(j + 1) & 3] >> (4 * s)) & 15);
      unsigned hw = __shfl(lo, base + l);
      unsigned long long b = (hw >> j) & 1;
      s = (s >> 1) | ((int)b << 3);
      pb |= b << j;
    }
  }
  bits[(size_t)pair * 16 + l16] = pb;
  map [(size_t)pair * 16 + l16] = (unsigned char)s;
}

// ---------------- K4: compose maps backward -> chunk end states ----------------
__global__ __launch_bounds__(256) void k_compose(const unsigned char* __restrict__ map,
                                                 unsigned char* __restrict__ Earr){
  const int seq = threadIdx.x;
  int s = 0;
  Earr[(size_t)NFULL * BB + seq] = 0;              // end state of tail chunk = 0
  #pragma unroll 4
  for (int c = NC - 1; c >= 1; --c){
    const uint4 mr = *(const uint4*)(map + ((size_t)c * BB + seq) * 16);
    unsigned wsel = (s < 8) ? ((s < 4) ? mr.x : mr.y) : ((s < 12) ? mr.z : mr.w);
    s = (wsel >> ((s & 3) * 8)) & 15;
    Earr[(size_t)(c - 1) * BB + seq] = (unsigned char)s;
  }
}

// ---------------- K5: emit = select hypothesis, expand bits to floats --------
__global__ __launch_bounds__(256) void k_emit(const unsigned long long* __restrict__ bits,
                                              const unsigned char* __restrict__ Earr,
                                              float* __restrict__ out){
  const int gt   = blockIdx.x * 256 + threadIdx.x;
  const int pair = gt >> 4;        // c*256+seq, c < 256
  const int l16  = gt & 15;
  const int c    = pair >> 8;
  const int seq  = pair & 255;
  const int e    = Earr[(size_t)c * BB + seq];             // broadcast in group
  const unsigned long long w = bits[(size_t)pair * 16 + e];// broadcast in group
  const int j0 = l16 * 4;
  float4 f;
  f.x = (float)((w >> (j0    )) & 1);
  f.y = (float)((w >> (j0 + 1)) & 1);
  f.z = (float)((w >> (j0 + 2)) & 1);
  f.w = (float)((w >> (j0 + 3)) & 1);
  *(float4*)(out + (size_t)seq * T_OUT + c * CHUNK + j0) = f;
}

extern "C" void kernel_launch(void* const* d_in, const int* in_sizes, int n_in,
                              void* d_out, int out_size, void* d_ws, size_t ws_size,
                              hipStream_t stream){
  const float* y = (const float*)d_in[0];
  const float* h = (const float*)d_in[1];
  float* out = (float*)d_out;

  const size_t CKPT_B = (size_t)NFULL * BB * 16 * 4;        // 4,194,304
  const size_t BITS_B = (size_t)NC * BB * 16 * 8;           // 8,421,376
  const size_t MAP_B  = (size_t)NC * BB * 16;               // 1,052,672
  const size_t E_B    = (size_t)NC * BB;                    //    65,792
  if (ws_size < CKPT_B + BITS_B + MAP_B + E_B) return;

  char* ws = (char*)d_ws;
  float*              ckpt = (float*)ws;
  unsigned long long* bits = (unsigned long long*)(ws + CKPT_B);
  unsigned char*      map  = (unsigned char*)(ws + CKPT_B + BITS_B);
  unsigned char*      Earr = (unsigned char*)(ws + CKPT_B + BITS_B + MAP_B);

  hipLaunchKernelGGL(k_forward, dim3(64),   dim3(192), 0, stream, y, h, ckpt);
  hipLaunchKernelGGL(k_replay,  dim3(4112), dim3(256), 0, stream, y, h, ckpt, bits, map);
  hipLaunchKernelGGL(k_compose, dim3(1),    dim3(256), 0, stream, map, Earr);
  hipLaunchKernelGGL(k_emit,    dim3(4096), dim3(256), 0, stream, bits, Earr, out);
}